// Round 1
// baseline (312.932 us; speedup 1.0000x reference)
//
#include <hip/hip_runtime.h>
#include <hip/hip_bf16.h>

// Problem: M=8, B=4, S=512, D=512, H=8, HD=64.
// Pipeline: wqkv^T+cast, wproj^T+cast -> QKV GEMM (bf16 MFMA, scatter to q/k/vT)
//           -> flash attention -> proj GEMM (fp32 out).

typedef unsigned short u16;
typedef __attribute__((ext_vector_type(8))) short short8;        // bf16x8 MFMA frag (4 VGPR)
typedef __attribute__((ext_vector_type(4))) float f32x4;         // MFMA acc frag
typedef __attribute__((ext_vector_type(4))) unsigned short u16x4;
typedef __attribute__((ext_vector_type(8))) unsigned short u16x8;

#define MFMA16(a, b, c) __builtin_amdgcn_mfma_f32_16x16x32_bf16((a), (b), (c), 0, 0, 0)

__device__ __forceinline__ u16 f2bf(float f) {
  union { __hip_bfloat16 h; u16 u; } cv;
  cv.h = __float2bfloat16(f);
  return cv.u;
}

// ---------------------------------------------------------------------------
// Weight transpose + fp32->bf16 cast: in [m][R][C] fp32 -> out [m][C][R] bf16
// ---------------------------------------------------------------------------
__global__ __launch_bounds__(256) void wtrans_kernel(const float* __restrict__ in,
                                                     u16* __restrict__ out, int R, int C) {
  __shared__ float t[32][33];
  int m = blockIdx.z;
  const float* pin = in + (size_t)m * R * C;
  u16* pout = out + (size_t)m * R * C;
  int c0 = blockIdx.x * 32, r0 = blockIdx.y * 32;
  int tx = threadIdx.x, ty = threadIdx.y;  // (32, 8)
#pragma unroll
  for (int i = 0; i < 4; ++i) {
    int r = ty + i * 8;
    t[r][tx] = pin[(size_t)(r0 + r) * C + c0 + tx];
  }
  __syncthreads();
#pragma unroll
  for (int i = 0; i < 4; ++i) {
    int r = ty + i * 8;
    pout[(size_t)(c0 + r) * R + r0 + tx] = f2bf(t[tx][r]);
  }
}

// ---------------------------------------------------------------------------
// QKV GEMM: x[m][2048][512] fp32  x  wT[m][1536][512] bf16 -> scatter:
//   q,k: [mb*8+h][s][hd] bf16 ; v transposed: vT [mb*8+h][hd][s] bf16
// 128x128 tile, BK=32, 4 waves (2x2), each wave 64x64 = 4x4 16x16 frags.
// ---------------------------------------------------------------------------
__global__ __launch_bounds__(256) void qkv_gemm_kernel(const float* __restrict__ X,
                                                       const u16* __restrict__ WT,
                                                       u16* __restrict__ Q,
                                                       u16* __restrict__ K,
                                                       u16* __restrict__ VT) {
  __shared__ u16 As[128][40];  // row stride 80B: 16B-aligned, 2-way max on b128
  __shared__ u16 Bs[128][40];  // staged transposed: Bs[col][k]
  int m = blockIdx.z;
  const float* A = X + (size_t)m * 2048 * 512;
  const u16* BT = WT + (size_t)m * 1536 * 512;
  int r0 = blockIdx.y * 128, c0 = blockIdx.x * 128;
  int t = threadIdx.x;
  int lane = t & 63, w = t >> 6;
  int wr = (w >> 1) * 64, wc = (w & 1) * 64;
  int fr = lane & 15, fc = lane >> 4;

  f32x4 acc[4][4];
#pragma unroll
  for (int i = 0; i < 4; ++i)
#pragma unroll
    for (int j = 0; j < 4; ++j) acc[i][j] = f32x4{0.f, 0.f, 0.f, 0.f};

  for (int kk = 0; kk < 512; kk += 32) {
    // stage A: 128 rows x 32 k, fp32 -> bf16
#pragma unroll
    for (int i = 0; i < 4; ++i) {
      int idx = t + i * 256;
      int row = idx >> 3, f4 = idx & 7;
      f32x4 v = *(const f32x4*)(A + (size_t)(r0 + row) * 512 + kk + f4 * 4);
      u16x4 pk = {f2bf(v[0]), f2bf(v[1]), f2bf(v[2]), f2bf(v[3])};
      *(u16x4*)&As[row][f4 * 4] = pk;
    }
    // stage B (already transposed in global): 128 cols x 32 k bf16
#pragma unroll
    for (int i = 0; i < 2; ++i) {
      int u = t + i * 256;
      int col = u >> 2, kc = u & 3;
      u16x8 v = *(const u16x8*)(BT + (size_t)(c0 + col) * 512 + kk + kc * 8);
      *(u16x8*)&Bs[col][kc * 8] = v;
    }
    __syncthreads();
    short8 af[4], bf[4];
#pragma unroll
    for (int i = 0; i < 4; ++i) af[i] = *(const short8*)&As[wr + i * 16 + fr][fc * 8];
#pragma unroll
    for (int j = 0; j < 4; ++j) bf[j] = *(const short8*)&Bs[wc + j * 16 + fr][fc * 8];
#pragma unroll
    for (int i = 0; i < 4; ++i)
#pragma unroll
      for (int j = 0; j < 4; ++j) acc[i][j] = MFMA16(af[i], bf[j], acc[i][j]);
    __syncthreads();
  }

  // epilogue scatter: C/D layout col=lane&15, row=(lane>>4)*4+r
  int seg = c0 >> 9;  // uniform per block: 0=q, 1=k, 2=v
#pragma unroll
  for (int i = 0; i < 4; ++i) {
#pragma unroll
    for (int j = 0; j < 4; ++j) {
#pragma unroll
      for (int r = 0; r < 4; ++r) {
        int grow = r0 + wr + i * 16 + fc * 4 + r;
        int gcol = c0 + wc + j * 16 + fr;
        int b = grow >> 9, s = grow & 511;
        int cc = gcol & 511;
        int hh = cc >> 6, hd = cc & 63;
        size_t headoff = (size_t)((m * 4 + b) * 8 + hh) * 32768;  // S*HD
        u16 val = f2bf(acc[i][j][r]);
        if (seg == 0)      Q[headoff + s * 64 + hd] = val;
        else if (seg == 1) K[headoff + s * 64 + hd] = val;
        else               VT[headoff + hd * 512 + s] = val;
      }
    }
  }
}

// ---------------------------------------------------------------------------
// Flash attention: one block = one (mb, h, 64-row q-tile); 4 waves x 16 q-rows.
// QK^T and PV via 16x16x32 MFMA; online softmax in exp2 domain.
// ---------------------------------------------------------------------------
__global__ __launch_bounds__(256) void attn_kernel(const u16* __restrict__ Qg,
                                                   const u16* __restrict__ Kg,
                                                   const u16* __restrict__ VTg,
                                                   u16* __restrict__ Yg) {
  __shared__ u16 P_lds[4][16][72];  // per-wave P relayout buffer
  int qt = blockIdx.x;   // q-tile 0..7
  int h = blockIdx.y;    // head 0..7
  int mb = blockIdx.z;   // m*4+b, 0..31
  int t = threadIdx.x, lane = t & 63, w = t >> 6;
  int fr = lane & 15, fc = lane >> 4;
  size_t hoff = ((size_t)mb * 8 + h) * 32768;
  const u16* Q = Qg + hoff;
  const u16* K = Kg + hoff;
  const u16* V = VTg + hoff;  // [hd][s]
  int r0 = qt * 64 + w * 16;

  short8 qf0 = *(const short8*)(Q + (size_t)(r0 + fr) * 64 + fc * 8);
  short8 qf1 = *(const short8*)(Q + (size_t)(r0 + fr) * 64 + 32 + fc * 8);

  f32x4 acc[4];
#pragma unroll
  for (int j = 0; j < 4; ++j) acc[j] = f32x4{0.f, 0.f, 0.f, 0.f};
  float mst[4] = {-1e30f, -1e30f, -1e30f, -1e30f};
  float lst[4] = {0.f, 0.f, 0.f, 0.f};
  const float SC = 0.125f * 1.44269504088896340736f;  // 1/sqrt(HD) * log2(e)

  for (int kt = 0; kt <= qt; ++kt) {
    int kb = kt * 64;
    f32x4 sf[4];
#pragma unroll
    for (int sub = 0; sub < 4; ++sub) {
      short8 kf0 = *(const short8*)(K + (size_t)(kb + sub * 16 + fr) * 64 + fc * 8);
      short8 kf1 = *(const short8*)(K + (size_t)(kb + sub * 16 + fr) * 64 + 32 + fc * 8);
      f32x4 z = f32x4{0.f, 0.f, 0.f, 0.f};
      z = MFMA16(qf1, kf1, z);
      sf[sub] = MFMA16(qf0, kf0, z);
    }
    float sv[4][4];
    float mt[4] = {-3e30f, -3e30f, -3e30f, -3e30f};
#pragma unroll
    for (int sub = 0; sub < 4; ++sub)
#pragma unroll
      for (int r = 0; r < 4; ++r) {
        float v = sf[sub][r] * SC;
        int kg = kb + sub * 16 + fr;
        int qg = r0 + fc * 4 + r;
        if (kg > qg) v = -1e30f;  // causal mask
        sv[sub][r] = v;
        mt[r] = fmaxf(mt[r], v);
      }
#pragma unroll
    for (int d = 1; d < 16; d <<= 1)
#pragma unroll
      for (int r = 0; r < 4; ++r) mt[r] = fmaxf(mt[r], __shfl_xor(mt[r], d));
    float al[4];
#pragma unroll
    for (int r = 0; r < 4; ++r) {
      float mn = fmaxf(mst[r], mt[r]);
      al[r] = exp2f(mst[r] - mn);
      mst[r] = mn;
    }
#pragma unroll
    for (int sub = 0; sub < 4; ++sub)
#pragma unroll
      for (int r = 0; r < 4; ++r) sv[sub][r] = exp2f(sv[sub][r] - mst[r]);
    float rs[4];
#pragma unroll
    for (int r = 0; r < 4; ++r) rs[r] = (sv[0][r] + sv[1][r]) + (sv[2][r] + sv[3][r]);
#pragma unroll
    for (int d = 1; d < 16; d <<= 1)
#pragma unroll
      for (int r = 0; r < 4; ++r) rs[r] += __shfl_xor(rs[r], d);
    f32x4 alv = {al[0], al[1], al[2], al[3]};
#pragma unroll
    for (int r = 0; r < 4; ++r) lst[r] = lst[r] * al[r] + rs[r];
#pragma unroll
    for (int j = 0; j < 4; ++j) acc[j] *= alv;

    // P (C-layout) -> LDS -> A-layout frags. Wave-private region: no barrier
    // needed; compiler orders ds_write->ds_read via lgkmcnt.
#pragma unroll
    for (int sub = 0; sub < 4; ++sub)
#pragma unroll
      for (int r = 0; r < 4; ++r)
        P_lds[w][fc * 4 + r][sub * 16 + fr] = f2bf(sv[sub][r]);
    short8 pa0 = *(const short8*)&P_lds[w][fr][fc * 8];
    short8 pa1 = *(const short8*)&P_lds[w][fr][32 + fc * 8];
#pragma unroll
    for (int j = 0; j < 4; ++j) {
      short8 vf0 = *(const short8*)(V + (size_t)(j * 16 + fr) * 512 + kb + fc * 8);
      short8 vf1 = *(const short8*)(V + (size_t)(j * 16 + fr) * 512 + kb + 32 + fc * 8);
      acc[j] = MFMA16(pa0, vf0, acc[j]);
      acc[j] = MFMA16(pa1, vf1, acc[j]);
    }
  }

  float inv[4];
#pragma unroll
  for (int r = 0; r < 4; ++r) inv[r] = 1.0f / lst[r];
#pragma unroll
  for (int j = 0; j < 4; ++j)
#pragma unroll
    for (int r = 0; r < 4; ++r) {
      int row = r0 + fc * 4 + r;
      Yg[((size_t)mb * 512 + row) * 512 + h * 64 + j * 16 + fr] = f2bf(acc[j][r] * inv[r]);
    }
}

// ---------------------------------------------------------------------------
// Projection GEMM: y[m][2048][512] bf16 x projT[m][512][512] bf16 -> out fp32
// ---------------------------------------------------------------------------
__global__ __launch_bounds__(256) void proj_gemm_kernel(const u16* __restrict__ Y,
                                                        const u16* __restrict__ PT,
                                                        float* __restrict__ OUT) {
  __shared__ u16 As[128][40];
  __shared__ u16 Bs[128][40];
  int m = blockIdx.z;
  const u16* A = Y + (size_t)m * 2048 * 512;
  const u16* BT = PT + (size_t)m * 512 * 512;
  float* C = OUT + (size_t)m * 2048 * 512;
  int r0 = blockIdx.y * 128, c0 = blockIdx.x * 128;
  int t = threadIdx.x;
  int lane = t & 63, w = t >> 6;
  int wr = (w >> 1) * 64, wc = (w & 1) * 64;
  int fr = lane & 15, fc = lane >> 4;

  f32x4 acc[4][4];
#pragma unroll
  for (int i = 0; i < 4; ++i)
#pragma unroll
    for (int j = 0; j < 4; ++j) acc[i][j] = f32x4{0.f, 0.f, 0.f, 0.f};

  for (int kk = 0; kk < 512; kk += 32) {
#pragma unroll
    for (int i = 0; i < 2; ++i) {
      int u = t + i * 256;
      int row = u >> 2, kc = u & 3;
      u16x8 v = *(const u16x8*)(A + (size_t)(r0 + row) * 512 + kk + kc * 8);
      *(u16x8*)&As[row][kc * 8] = v;
    }
#pragma unroll
    for (int i = 0; i < 2; ++i) {
      int u = t + i * 256;
      int col = u >> 2, kc = u & 3;
      u16x8 v = *(const u16x8*)(BT + (size_t)(c0 + col) * 512 + kk + kc * 8);
      *(u16x8*)&Bs[col][kc * 8] = v;
    }
    __syncthreads();
    short8 af[4], bf[4];
#pragma unroll
    for (int i = 0; i < 4; ++i) af[i] = *(const short8*)&As[wr + i * 16 + fr][fc * 8];
#pragma unroll
    for (int j = 0; j < 4; ++j) bf[j] = *(const short8*)&Bs[wc + j * 16 + fr][fc * 8];
#pragma unroll
    for (int i = 0; i < 4; ++i)
#pragma unroll
      for (int j = 0; j < 4; ++j) acc[i][j] = MFMA16(af[i], bf[j], acc[i][j]);
    __syncthreads();
  }
#pragma unroll
  for (int i = 0; i < 4; ++i)
#pragma unroll
    for (int j = 0; j < 4; ++j)
#pragma unroll
      for (int r = 0; r < 4; ++r) {
        int grow = r0 + wr + i * 16 + fc * 4 + r;
        int gcol = c0 + wc + j * 16 + fr;
        C[(size_t)grow * 512 + gcol] = acc[i][j][r];
      }
}

// ---------------------------------------------------------------------------
extern "C" void kernel_launch(void* const* d_in, const int* in_sizes, int n_in,
                              void* d_out, int out_size, void* d_ws, size_t ws_size,
                              hipStream_t stream) {
  const float* x = (const float*)d_in[0];      // [8][4][512][512]
  const float* wqkv = (const float*)d_in[1];   // [8][512][1536]
  const float* wproj = (const float*)d_in[2];  // [8][512][512]
  float* out = (float*)d_out;                  // [8][4][512][512]

  u16* p = (u16*)d_ws;
  u16* wqkvT = p;  p += (size_t)8 * 1536 * 512;  // bf16 [m][1536][512]
  u16* wprojT = p; p += (size_t)8 * 512 * 512;   // bf16 [m][512][512]
  u16* qb = p;     p += (size_t)8388608;         // bf16 [mb*8+h][512][64]
  u16* kb = p;     p += (size_t)8388608;         // bf16 [mb*8+h][512][64]
  u16* vtb = p;    p += (size_t)8388608;         // bf16 [mb*8+h][64][512]
  u16* yb = p;     p += (size_t)8388608;         // bf16 [m][b][512][512]
  // total ws use: ~84 MB

  wtrans_kernel<<<dim3(48, 16, 8), dim3(32, 8), 0, stream>>>(wqkv, wqkvT, 512, 1536);
  wtrans_kernel<<<dim3(16, 16, 8), dim3(32, 8), 0, stream>>>(wproj, wprojT, 512, 512);
  qkv_gemm_kernel<<<dim3(12, 16, 8), 256, 0, stream>>>(x, wqkvT, qb, kb, vtb);
  attn_kernel<<<dim3(8, 8, 32), 256, 0, stream>>>(qb, kb, vtb, yb);
  proj_gemm_kernel<<<dim3(4, 16, 8), 256, 0, stream>>>(yb, wprojT, out);
}

// Round 2
// 225.937 us; speedup vs baseline: 1.3850x; 1.3850x over previous
//
#include <hip/hip_runtime.h>
#include <hip/hip_bf16.h>

// Problem: M=8, B=4, S=512, D=512, H=8, HD=64.
// Pipeline: wqkv^T+cast, wproj^T+cast -> QKV GEMM (bf16 MFMA, scatter to q/k/vT)
//           -> flash attention (transposed S/P/Y, LDS-staged K/V) -> proj GEMM.

typedef unsigned short u16;
typedef unsigned int u32;
typedef __attribute__((ext_vector_type(8))) short short8;        // bf16x8 MFMA frag (4 VGPR)
typedef __attribute__((ext_vector_type(4))) float f32x4;         // MFMA acc frag
typedef __attribute__((ext_vector_type(4))) unsigned short u16x4;
typedef __attribute__((ext_vector_type(8))) unsigned short u16x8;
typedef __attribute__((ext_vector_type(2))) unsigned int u32x2;

#define MFMA16(a, b, c) __builtin_amdgcn_mfma_f32_16x16x32_bf16((a), (b), (c), 0, 0, 0)

__device__ __forceinline__ u16 f2bf(float f) {
  union { __hip_bfloat16 h; u16 u; } cv;
  cv.h = __float2bfloat16(f);
  return cv.u;
}

// ---------------------------------------------------------------------------
// Weight transpose + fp32->bf16 cast: in [m][R][C] fp32 -> out [m][C][R] bf16
// ---------------------------------------------------------------------------
__global__ __launch_bounds__(256) void wtrans_kernel(const float* __restrict__ in,
                                                     u16* __restrict__ out, int R, int C) {
  __shared__ float t[32][33];
  int m = blockIdx.z;
  const float* pin = in + (size_t)m * R * C;
  u16* pout = out + (size_t)m * R * C;
  int c0 = blockIdx.x * 32, r0 = blockIdx.y * 32;
  int tx = threadIdx.x, ty = threadIdx.y;  // (32, 8)
#pragma unroll
  for (int i = 0; i < 4; ++i) {
    int r = ty + i * 8;
    t[r][tx] = pin[(size_t)(r0 + r) * C + c0 + tx];
  }
  __syncthreads();
#pragma unroll
  for (int i = 0; i < 4; ++i) {
    int r = ty + i * 8;
    pout[(size_t)(c0 + r) * R + r0 + tx] = f2bf(t[tx][r]);
  }
}

// ---------------------------------------------------------------------------
// QKV GEMM: x[m][2048][512] fp32  x  wT[m][1536][512] bf16 -> scatter:
//   q,k: [mb*8+h][s][hd] bf16 ; v transposed: vT [mb*8+h][hd][s] bf16
// ---------------------------------------------------------------------------
__global__ __launch_bounds__(256) void qkv_gemm_kernel(const float* __restrict__ X,
                                                       const u16* __restrict__ WT,
                                                       u16* __restrict__ Q,
                                                       u16* __restrict__ K,
                                                       u16* __restrict__ VT) {
  __shared__ u16 As[128][40];
  __shared__ u16 Bs[128][40];
  int m = blockIdx.z;
  const float* A = X + (size_t)m * 2048 * 512;
  const u16* BT = WT + (size_t)m * 1536 * 512;
  int r0 = blockIdx.y * 128, c0 = blockIdx.x * 128;
  int t = threadIdx.x;
  int lane = t & 63, w = t >> 6;
  int wr = (w >> 1) * 64, wc = (w & 1) * 64;
  int fr = lane & 15, fc = lane >> 4;

  f32x4 acc[4][4];
#pragma unroll
  for (int i = 0; i < 4; ++i)
#pragma unroll
    for (int j = 0; j < 4; ++j) acc[i][j] = f32x4{0.f, 0.f, 0.f, 0.f};

  for (int kk = 0; kk < 512; kk += 32) {
#pragma unroll
    for (int i = 0; i < 4; ++i) {
      int idx = t + i * 256;
      int row = idx >> 3, f4 = idx & 7;
      f32x4 v = *(const f32x4*)(A + (size_t)(r0 + row) * 512 + kk + f4 * 4);
      u16x4 pk = {f2bf(v[0]), f2bf(v[1]), f2bf(v[2]), f2bf(v[3])};
      *(u16x4*)&As[row][f4 * 4] = pk;
    }
#pragma unroll
    for (int i = 0; i < 2; ++i) {
      int u = t + i * 256;
      int col = u >> 2, kc = u & 3;
      u16x8 v = *(const u16x8*)(BT + (size_t)(c0 + col) * 512 + kk + kc * 8);
      *(u16x8*)&Bs[col][kc * 8] = v;
    }
    __syncthreads();
    short8 af[4], bf[4];
#pragma unroll
    for (int i = 0; i < 4; ++i) af[i] = *(const short8*)&As[wr + i * 16 + fr][fc * 8];
#pragma unroll
    for (int j = 0; j < 4; ++j) bf[j] = *(const short8*)&Bs[wc + j * 16 + fr][fc * 8];
#pragma unroll
    for (int i = 0; i < 4; ++i)
#pragma unroll
      for (int j = 0; j < 4; ++j) acc[i][j] = MFMA16(af[i], bf[j], acc[i][j]);
    __syncthreads();
  }

  int seg = c0 >> 9;  // uniform per block: 0=q, 1=k, 2=v
#pragma unroll
  for (int i = 0; i < 4; ++i) {
#pragma unroll
    for (int j = 0; j < 4; ++j) {
#pragma unroll
      for (int r = 0; r < 4; ++r) {
        int grow = r0 + wr + i * 16 + fc * 4 + r;
        int gcol = c0 + wc + j * 16 + fr;
        int b = grow >> 9, s = grow & 511;
        int cc = gcol & 511;
        int hh = cc >> 6, hd = cc & 63;
        size_t headoff = (size_t)((m * 4 + b) * 8 + hh) * 32768;  // S*HD
        u16 val = f2bf(acc[i][j][r]);
        if (seg == 0)      Q[headoff + s * 64 + hd] = val;
        else if (seg == 1) K[headoff + s * 64 + hd] = val;
        else               VT[headoff + hd * 512 + s] = val;
      }
    }
  }
}

// ---------------------------------------------------------------------------
// Flash attention, transposed pipeline.
// Grid: 2048 1-D blocks; bid>>8 = qt (0..7), bid&255 = head g (h=g&7, mb=g>>3)
//   -> all 8 qt-blocks of a head land on the same XCD (bid%8 == g%8).
// Block: 4 waves x 16 q-rows (64 q rows). K/V^T tiles (64 x 64) staged in LDS,
// double-buffered, shared by all waves.
// S^T = MFMA(A=K, B=Q): lane holds q = lane&15 (fixed), 16 k-values.
// Softmax per-lane + 2 shfl_xor. P^T packed to LDS (b64). Y^T = MFMA(A=V^T, B=P^T):
// C col = q = lane&15 -> rescale/normalize entirely lane-local.
// ---------------------------------------------------------------------------
__global__ __launch_bounds__(256) void attn_kernel(const u16* __restrict__ Qg,
                                                   const u16* __restrict__ Kg,
                                                   const u16* __restrict__ VTg,
                                                   u16* __restrict__ Yg) {
  __shared__ u16 Ks[2][64][72];   // [buf][k-row][d]
  __shared__ u16 Vs[2][64][72];   // [buf][d][k]
  __shared__ u16 Pl[4][16][72];   // [wave][q][k]
  int bid = blockIdx.x;
  int qt = bid >> 8;
  int g = bid & 255;
  int h = g & 7, mb = g >> 3;
  int t = threadIdx.x, lane = t & 63, w = t >> 6;
  int fr = lane & 15, fc = lane >> 4;
  size_t hoff = ((size_t)mb * 8 + h) * 32768;
  const u16* Q = Qg + hoff;
  const u16* K = Kg + hoff;
  const u16* V = VTg + hoff;  // [hd][s]
  int qrow = qt * 64 + w * 16 + fr;
  const float SC = 0.125f * 1.44269504088896340736f;  // 1/sqrt(HD) * log2(e)

  // Q as B-operand fragments: col=q=fr, k=d
  short8 qf0 = *(const short8*)(Q + (size_t)qrow * 64 + fc * 8);
  short8 qf1 = *(const short8*)(Q + (size_t)qrow * 64 + 32 + fc * 8);

  f32x4 acc[4];  // acc[dt] = Y^T[dt*16 + fc*4 + r][q=fr]
#pragma unroll
  for (int d = 0; d < 4; ++d) acc[d] = f32x4{0.f, 0.f, 0.f, 0.f};
  float mst = -1e30f, lst = 0.f;

  // staging geometry: 16B unit u covers row u>>3, halfword col (u&7)*8
  int u0 = 2 * t, u1 = 2 * t + 1;
  int kr0 = u0 >> 3, kc0 = (u0 & 7) * 8;
  int kr1 = u1 >> 3, kc1 = (u1 & 7) * 8;

  // prologue: stage tile kt=0 into buffer 0
  {
    u16x8 a0 = *(const u16x8*)(K + (size_t)kr0 * 64 + kc0);
    u16x8 a1 = *(const u16x8*)(K + (size_t)kr1 * 64 + kc1);
    u16x8 b0 = *(const u16x8*)(V + (size_t)kr0 * 512 + kc0);
    u16x8 b1 = *(const u16x8*)(V + (size_t)kr1 * 512 + kc1);
    *(u16x8*)&Ks[0][kr0][kc0] = a0;
    *(u16x8*)&Ks[0][kr1][kc1] = a1;
    *(u16x8*)&Vs[0][kr0][kc0] = b0;
    *(u16x8*)&Vs[0][kr1][kc1] = b1;
  }
  __syncthreads();

  for (int kt = 0; kt <= qt; ++kt) {
    int cur = kt & 1;
    bool pref = kt < qt;
    u16x8 nk0, nk1, nv0, nv1;
    if (pref) {  // issue next-tile global loads early; they retire under compute
      int kbn = (kt + 1) * 64;
      nk0 = *(const u16x8*)(K + (size_t)(kbn + kr0) * 64 + kc0);
      nk1 = *(const u16x8*)(K + (size_t)(kbn + kr1) * 64 + kc1);
      nv0 = *(const u16x8*)(V + (size_t)kr0 * 512 + kbn + kc0);
      nv1 = *(const u16x8*)(V + (size_t)kr1 * 512 + kbn + kc1);
    }

    // QK^T (transposed): S^T[k][q], 4 sub-tiles of 16 k
    f32x4 st[4];
#pragma unroll
    for (int sub = 0; sub < 4; ++sub) {
      short8 kf0 = *(const short8*)&Ks[cur][sub * 16 + fr][fc * 8];
      short8 kf1 = *(const short8*)&Ks[cur][sub * 16 + fr][32 + fc * 8];
      f32x4 z = f32x4{0.f, 0.f, 0.f, 0.f};
      z = MFMA16(kf0, qf0, z);
      st[sub] = MFMA16(kf1, qf1, z);
    }

    // softmax, all state per-lane (q = fr)
    float p[4][4];
    float mt = -3e30f;
    bool diag = (kt == qt);
    int qloc = w * 16 + fr;
#pragma unroll
    for (int sub = 0; sub < 4; ++sub)
#pragma unroll
      for (int r = 0; r < 4; ++r) {
        float v = st[sub][r] * SC;
        if (diag && (sub * 16 + fc * 4 + r) > qloc) v = -1e30f;
        p[sub][r] = v;
        mt = fmaxf(mt, v);
      }
    mt = fmaxf(mt, __shfl_xor(mt, 16));
    mt = fmaxf(mt, __shfl_xor(mt, 32));
    float mn = fmaxf(mst, mt);
    float al = __builtin_amdgcn_exp2f(mst - mn);
    mst = mn;
    float rs = 0.f;
#pragma unroll
    for (int sub = 0; sub < 4; ++sub)
#pragma unroll
      for (int r = 0; r < 4; ++r) {
        float e = __builtin_amdgcn_exp2f(p[sub][r] - mn);
        p[sub][r] = e;
        rs += e;
      }
    rs += __shfl_xor(rs, 16);
    rs += __shfl_xor(rs, 32);
    lst = lst * al + rs;
#pragma unroll
    for (int d = 0; d < 4; ++d) acc[d] *= al;

    // P^T -> LDS (each lane's 4 values are k-contiguous: b64 packed writes)
#pragma unroll
    for (int sub = 0; sub < 4; ++sub) {
      u32 lo = (u32)f2bf(p[sub][0]) | ((u32)f2bf(p[sub][1]) << 16);
      u32 hi = (u32)f2bf(p[sub][2]) | ((u32)f2bf(p[sub][3]) << 16);
      *(u32x2*)&Pl[w][fr][sub * 16 + fc * 4] = u32x2{lo, hi};
    }

    // PV (transposed): Y^T[d][q] += V^T[d][k] . P^T[k][q]
#pragma unroll
    for (int dt = 0; dt < 4; ++dt)
#pragma unroll
      for (int kc = 0; kc < 2; ++kc) {
        short8 vf = *(const short8*)&Vs[cur][dt * 16 + fr][kc * 32 + fc * 8];
        short8 pb = *(const short8*)&Pl[w][fr][kc * 32 + fc * 8];
        acc[dt] = MFMA16(vf, pb, acc[dt]);
      }

    if (pref) {  // write prefetched tile into other buffer
      *(u16x8*)&Ks[cur ^ 1][kr0][kc0] = nk0;
      *(u16x8*)&Ks[cur ^ 1][kr1][kc1] = nk1;
      *(u16x8*)&Vs[cur ^ 1][kr0][kc0] = nv0;
      *(u16x8*)&Vs[cur ^ 1][kr1][kc1] = nv1;
    }
    __syncthreads();
  }

  float inv = 1.0f / lst;
#pragma unroll
  for (int dt = 0; dt < 4; ++dt) {
    u16x4 o = {f2bf(acc[dt][0] * inv), f2bf(acc[dt][1] * inv),
               f2bf(acc[dt][2] * inv), f2bf(acc[dt][3] * inv)};
    *(u16x4*)(Yg + ((size_t)mb * 512 + qrow) * 512 + h * 64 + dt * 16 + fc * 4) = o;
  }
}

// ---------------------------------------------------------------------------
// Projection GEMM: y[m][2048][512] bf16 x projT[m][512][512] bf16 -> out fp32
// ---------------------------------------------------------------------------
__global__ __launch_bounds__(256) void proj_gemm_kernel(const u16* __restrict__ Y,
                                                        const u16* __restrict__ PT,
                                                        float* __restrict__ OUT) {
  __shared__ u16 As[128][40];
  __shared__ u16 Bs[128][40];
  int m = blockIdx.z;
  const u16* A = Y + (size_t)m * 2048 * 512;
  const u16* BT = PT + (size_t)m * 512 * 512;
  float* C = OUT + (size_t)m * 2048 * 512;
  int r0 = blockIdx.y * 128, c0 = blockIdx.x * 128;
  int t = threadIdx.x;
  int lane = t & 63, w = t >> 6;
  int wr = (w >> 1) * 64, wc = (w & 1) * 64;
  int fr = lane & 15, fc = lane >> 4;

  f32x4 acc[4][4];
#pragma unroll
  for (int i = 0; i < 4; ++i)
#pragma unroll
    for (int j = 0; j < 4; ++j) acc[i][j] = f32x4{0.f, 0.f, 0.f, 0.f};

  for (int kk = 0; kk < 512; kk += 32) {
#pragma unroll
    for (int i = 0; i < 2; ++i) {
      int u = t + i * 256;
      int row = u >> 2, kc = u & 3;
      u16x8 v = *(const u16x8*)(A + (size_t)(r0 + row) * 512 + kk + kc * 8);
      *(u16x8*)&As[row][kc * 8] = v;
    }
#pragma unroll
    for (int i = 0; i < 2; ++i) {
      int u = t + i * 256;
      int col = u >> 2, kc = u & 3;
      u16x8 v = *(const u16x8*)(BT + (size_t)(c0 + col) * 512 + kk + kc * 8);
      *(u16x8*)&Bs[col][kc * 8] = v;
    }
    __syncthreads();
    short8 af[4], bf[4];
#pragma unroll
    for (int i = 0; i < 4; ++i) af[i] = *(const short8*)&As[wr + i * 16 + fr][fc * 8];
#pragma unroll
    for (int j = 0; j < 4; ++j) bf[j] = *(const short8*)&Bs[wc + j * 16 + fr][fc * 8];
#pragma unroll
    for (int i = 0; i < 4; ++i)
#pragma unroll
      for (int j = 0; j < 4; ++j) acc[i][j] = MFMA16(af[i], bf[j], acc[i][j]);
    __syncthreads();
  }
#pragma unroll
  for (int i = 0; i < 4; ++i)
#pragma unroll
    for (int j = 0; j < 4; ++j)
#pragma unroll
      for (int r = 0; r < 4; ++r) {
        int grow = r0 + wr + i * 16 + fc * 4 + r;
        int gcol = c0 + wc + j * 16 + fr;
        C[(size_t)grow * 512 + gcol] = acc[i][j][r];
      }
}

// ---------------------------------------------------------------------------
extern "C" void kernel_launch(void* const* d_in, const int* in_sizes, int n_in,
                              void* d_out, int out_size, void* d_ws, size_t ws_size,
                              hipStream_t stream) {
  const float* x = (const float*)d_in[0];      // [8][4][512][512]
  const float* wqkv = (const float*)d_in[1];   // [8][512][1536]
  const float* wproj = (const float*)d_in[2];  // [8][512][512]
  float* out = (float*)d_out;                  // [8][4][512][512]

  u16* p = (u16*)d_ws;
  u16* wqkvT = p;  p += (size_t)8 * 1536 * 512;  // bf16 [m][1536][512]
  u16* wprojT = p; p += (size_t)8 * 512 * 512;   // bf16 [m][512][512]
  u16* qb = p;     p += (size_t)8388608;         // bf16 [mb*8+h][512][64]
  u16* kb = p;     p += (size_t)8388608;         // bf16 [mb*8+h][512][64]
  u16* vtb = p;    p += (size_t)8388608;         // bf16 [mb*8+h][64][512]
  u16* yb = p;     p += (size_t)8388608;         // bf16 [m][b][512][512]

  wtrans_kernel<<<dim3(48, 16, 8), dim3(32, 8), 0, stream>>>(wqkv, wqkvT, 512, 1536);
  wtrans_kernel<<<dim3(16, 16, 8), dim3(32, 8), 0, stream>>>(wproj, wprojT, 512, 512);
  qkv_gemm_kernel<<<dim3(12, 16, 8), 256, 0, stream>>>(x, wqkvT, qb, kb, vtb);
  attn_kernel<<<2048, 256, 0, stream>>>(qb, kb, vtb, yb);
  proj_gemm_kernel<<<dim3(4, 16, 8), 256, 0, stream>>>(yb, wprojT, out);
}

// Round 3
// 220.738 us; speedup vs baseline: 1.4177x; 1.0236x over previous
//
#include <hip/hip_runtime.h>
#include <hip/hip_bf16.h>

// Problem: M=8, B=4, S=512, D=512, H=8, HD=64.
// Pipeline: xcast (fp32->bf16), wqkv^T+cast, wproj^T+cast
//           -> QKV GEMM (m97 structure: global_load_lds, bf16 MFMA, scatter q/k/vT)
//           -> flash attention (transposed S/P/Y, LDS-staged K/V) -> proj GEMM.

typedef unsigned short u16;
typedef unsigned int u32;
typedef __attribute__((ext_vector_type(8))) short short8;        // bf16x8 MFMA frag (4 VGPR)
typedef __attribute__((ext_vector_type(4))) float f32x4;         // MFMA acc frag
typedef __attribute__((ext_vector_type(4))) unsigned short u16x4;
typedef __attribute__((ext_vector_type(8))) unsigned short u16x8;
typedef __attribute__((ext_vector_type(2))) unsigned int u32x2;

#define MFMA16(a, b, c) __builtin_amdgcn_mfma_f32_16x16x32_bf16((a), (b), (c), 0, 0, 0)

__device__ __forceinline__ u16 f2bf(float f) {
  union { __hip_bfloat16 h; u16 u; } cv;
  cv.h = __float2bfloat16(f);
  return cv.u;
}

// async global->LDS, 16B per lane; lds base must be wave-uniform.
__device__ __forceinline__ void gl_lds16(const u16* g, u16* l) {
  __builtin_amdgcn_global_load_lds(
      (const __attribute__((address_space(1))) void*)g,
      (__attribute__((address_space(3))) void*)l, 16, 0, 0);
}

// ---------------------------------------------------------------------------
// X cast: fp32 [n] -> bf16 [n], vectorized 8/thread, grid-stride.
// ---------------------------------------------------------------------------
__global__ __launch_bounds__(256) void xcast_kernel(const float* __restrict__ in,
                                                    u16* __restrict__ out, long n8) {
  long stride = (long)gridDim.x * 256;
  for (long i = blockIdx.x * 256L + threadIdx.x; i < n8; i += stride) {
    f32x4 a = *(const f32x4*)(in + i * 8);
    f32x4 b = *(const f32x4*)(in + i * 8 + 4);
    u16x8 o = {f2bf(a[0]), f2bf(a[1]), f2bf(a[2]), f2bf(a[3]),
               f2bf(b[0]), f2bf(b[1]), f2bf(b[2]), f2bf(b[3])};
    *(u16x8*)(out + i * 8) = o;
  }
}

// ---------------------------------------------------------------------------
// Weight transpose + fp32->bf16 cast: in [m][R][C] fp32 -> out [m][C][R] bf16
// ---------------------------------------------------------------------------
__global__ __launch_bounds__(256) void wtrans_kernel(const float* __restrict__ in,
                                                     u16* __restrict__ out, int R, int C) {
  __shared__ float t[32][33];
  int m = blockIdx.z;
  const float* pin = in + (size_t)m * R * C;
  u16* pout = out + (size_t)m * R * C;
  int c0 = blockIdx.x * 32, r0 = blockIdx.y * 32;
  int tx = threadIdx.x, ty = threadIdx.y;  // (32, 8)
#pragma unroll
  for (int i = 0; i < 4; ++i) {
    int r = ty + i * 8;
    t[r][tx] = pin[(size_t)(r0 + r) * C + c0 + tx];
  }
  __syncthreads();
#pragma unroll
  for (int i = 0; i < 4; ++i) {
    int r = ty + i * 8;
    pout[(size_t)(c0 + r) * R + r0 + tx] = f2bf(t[tx][r]);
  }
}

// ---------------------------------------------------------------------------
// QKV GEMM (m97 structure): xb[m][2048][512] bf16 x wT[m][1536][512] bf16.
// 128x128 tile, BK=32, 4 waves (2x2), global_load_lds width-16 staging into
// linear [128][32] LDS tiles. Scatter epilogue to q/k/vT head layouts.
// ---------------------------------------------------------------------------
__global__ __launch_bounds__(256) void qkv_gemm_kernel(const u16* __restrict__ XB,
                                                       const u16* __restrict__ WT,
                                                       u16* __restrict__ Q,
                                                       u16* __restrict__ K,
                                                       u16* __restrict__ VT) {
  __shared__ __attribute__((aligned(16))) u16 As[128 * 32];  // linear [row][k]
  __shared__ __attribute__((aligned(16))) u16 Bs[128 * 32];  // linear [col][k]
  int m = blockIdx.z;
  const u16* A = XB + (size_t)m * 2048 * 512;
  const u16* BT = WT + (size_t)m * 1536 * 512;
  int r0 = blockIdx.y * 128, c0 = blockIdx.x * 128;
  int t = threadIdx.x;
  int lane = t & 63, w = t >> 6;
  int wr = (w >> 1) * 64, wc = (w & 1) * 64;
  int fr = lane & 15, fc = lane >> 4;

  // staging: unit u (16B) covers row u>>2, k-chunk (u&3)*8; wave w owns units
  // [w*128, w*128+128) via 2 calls of 64 lanes.
  int u0 = w * 128 + lane;        // call 0
  int u1 = w * 128 + 64 + lane;   // call 1
  int ar0 = u0 >> 2, ak0 = (u0 & 3) * 8;
  int ar1 = u1 >> 2, ak1 = (u1 & 3) * 8;
  u16* lbase0 = &As[0] + (size_t)(w * 128) * 8;        // As/Bs share unit geometry
  u16* lbase1 = &As[0] + (size_t)(w * 128 + 64) * 8;
  u16* lbb0 = &Bs[0] + (size_t)(w * 128) * 8;
  u16* lbb1 = &Bs[0] + (size_t)(w * 128 + 64) * 8;

  f32x4 acc[4][4];
#pragma unroll
  for (int i = 0; i < 4; ++i)
#pragma unroll
    for (int j = 0; j < 4; ++j) acc[i][j] = f32x4{0.f, 0.f, 0.f, 0.f};

  for (int kk = 0; kk < 512; kk += 32) {
    gl_lds16(A + (size_t)(r0 + ar0) * 512 + kk + ak0, lbase0);
    gl_lds16(A + (size_t)(r0 + ar1) * 512 + kk + ak1, lbase1);
    gl_lds16(BT + (size_t)(c0 + ar0) * 512 + kk + ak0, lbb0);
    gl_lds16(BT + (size_t)(c0 + ar1) * 512 + kk + ak1, lbb1);
    __syncthreads();  // drains vmcnt + lgkmcnt
    short8 af[4], bf[4];
#pragma unroll
    for (int i = 0; i < 4; ++i) af[i] = *(const short8*)&As[(wr + i * 16 + fr) * 32 + fc * 8];
#pragma unroll
    for (int j = 0; j < 4; ++j) bf[j] = *(const short8*)&Bs[(wc + j * 16 + fr) * 32 + fc * 8];
#pragma unroll
    for (int i = 0; i < 4; ++i)
#pragma unroll
      for (int j = 0; j < 4; ++j) acc[i][j] = MFMA16(af[i], bf[j], acc[i][j]);
    __syncthreads();
  }

  int seg = c0 >> 9;  // uniform per block: 0=q, 1=k, 2=v
#pragma unroll
  for (int i = 0; i < 4; ++i) {
#pragma unroll
    for (int j = 0; j < 4; ++j) {
#pragma unroll
      for (int r = 0; r < 4; ++r) {
        int grow = r0 + wr + i * 16 + fc * 4 + r;
        int gcol = c0 + wc + j * 16 + fr;
        int b = grow >> 9, s = grow & 511;
        int cc = gcol & 511;
        int hh = cc >> 6, hd = cc & 63;
        size_t headoff = (size_t)((m * 4 + b) * 8 + hh) * 32768;  // S*HD
        u16 val = f2bf(acc[i][j][r]);
        if (seg == 0)      Q[headoff + s * 64 + hd] = val;
        else if (seg == 1) K[headoff + s * 64 + hd] = val;
        else               VT[headoff + hd * 512 + s] = val;
      }
    }
  }
}

// ---------------------------------------------------------------------------
// Flash attention, transposed pipeline (unchanged from R1).
// ---------------------------------------------------------------------------
__global__ __launch_bounds__(256) void attn_kernel(const u16* __restrict__ Qg,
                                                   const u16* __restrict__ Kg,
                                                   const u16* __restrict__ VTg,
                                                   u16* __restrict__ Yg) {
  __shared__ u16 Ks[2][64][72];   // [buf][k-row][d]
  __shared__ u16 Vs[2][64][72];   // [buf][d][k]
  __shared__ u16 Pl[4][16][72];   // [wave][q][k]
  int bid = blockIdx.x;
  int qt = bid >> 8;
  int g = bid & 255;
  int h = g & 7, mb = g >> 3;
  int t = threadIdx.x, lane = t & 63, w = t >> 6;
  int fr = lane & 15, fc = lane >> 4;
  size_t hoff = ((size_t)mb * 8 + h) * 32768;
  const u16* Q = Qg + hoff;
  const u16* K = Kg + hoff;
  const u16* V = VTg + hoff;  // [hd][s]
  int qrow = qt * 64 + w * 16 + fr;
  const float SC = 0.125f * 1.44269504088896340736f;  // 1/sqrt(HD) * log2(e)

  short8 qf0 = *(const short8*)(Q + (size_t)qrow * 64 + fc * 8);
  short8 qf1 = *(const short8*)(Q + (size_t)qrow * 64 + 32 + fc * 8);

  f32x4 acc[4];  // acc[dt] = Y^T[dt*16 + fc*4 + r][q=fr]
#pragma unroll
  for (int d = 0; d < 4; ++d) acc[d] = f32x4{0.f, 0.f, 0.f, 0.f};
  float mst = -1e30f, lst = 0.f;

  int u0 = 2 * t, u1 = 2 * t + 1;
  int kr0 = u0 >> 3, kc0 = (u0 & 7) * 8;
  int kr1 = u1 >> 3, kc1 = (u1 & 7) * 8;

  {
    u16x8 a0 = *(const u16x8*)(K + (size_t)kr0 * 64 + kc0);
    u16x8 a1 = *(const u16x8*)(K + (size_t)kr1 * 64 + kc1);
    u16x8 b0 = *(const u16x8*)(V + (size_t)kr0 * 512 + kc0);
    u16x8 b1 = *(const u16x8*)(V + (size_t)kr1 * 512 + kc1);
    *(u16x8*)&Ks[0][kr0][kc0] = a0;
    *(u16x8*)&Ks[0][kr1][kc1] = a1;
    *(u16x8*)&Vs[0][kr0][kc0] = b0;
    *(u16x8*)&Vs[0][kr1][kc1] = b1;
  }
  __syncthreads();

  for (int kt = 0; kt <= qt; ++kt) {
    int cur = kt & 1;
    bool pref = kt < qt;
    u16x8 nk0, nk1, nv0, nv1;
    if (pref) {
      int kbn = (kt + 1) * 64;
      nk0 = *(const u16x8*)(K + (size_t)(kbn + kr0) * 64 + kc0);
      nk1 = *(const u16x8*)(K + (size_t)(kbn + kr1) * 64 + kc1);
      nv0 = *(const u16x8*)(V + (size_t)kr0 * 512 + kbn + kc0);
      nv1 = *(const u16x8*)(V + (size_t)kr1 * 512 + kbn + kc1);
    }

    f32x4 st[4];
#pragma unroll
    for (int sub = 0; sub < 4; ++sub) {
      short8 kf0 = *(const short8*)&Ks[cur][sub * 16 + fr][fc * 8];
      short8 kf1 = *(const short8*)&Ks[cur][sub * 16 + fr][32 + fc * 8];
      f32x4 z = f32x4{0.f, 0.f, 0.f, 0.f};
      z = MFMA16(kf0, qf0, z);
      st[sub] = MFMA16(kf1, qf1, z);
    }

    float p[4][4];
    float mt = -3e30f;
    bool diag = (kt == qt);
    int qloc = w * 16 + fr;
#pragma unroll
    for (int sub = 0; sub < 4; ++sub)
#pragma unroll
      for (int r = 0; r < 4; ++r) {
        float v = st[sub][r] * SC;
        if (diag && (sub * 16 + fc * 4 + r) > qloc) v = -1e30f;
        p[sub][r] = v;
        mt = fmaxf(mt, v);
      }
    mt = fmaxf(mt, __shfl_xor(mt, 16));
    mt = fmaxf(mt, __shfl_xor(mt, 32));
    float mn = fmaxf(mst, mt);
    float al = __builtin_amdgcn_exp2f(mst - mn);
    mst = mn;
    float rs = 0.f;
#pragma unroll
    for (int sub = 0; sub < 4; ++sub)
#pragma unroll
      for (int r = 0; r < 4; ++r) {
        float e = __builtin_amdgcn_exp2f(p[sub][r] - mn);
        p[sub][r] = e;
        rs += e;
      }
    rs += __shfl_xor(rs, 16);
    rs += __shfl_xor(rs, 32);
    lst = lst * al + rs;
#pragma unroll
    for (int d = 0; d < 4; ++d) acc[d] *= al;

#pragma unroll
    for (int sub = 0; sub < 4; ++sub) {
      u32 lo = (u32)f2bf(p[sub][0]) | ((u32)f2bf(p[sub][1]) << 16);
      u32 hi = (u32)f2bf(p[sub][2]) | ((u32)f2bf(p[sub][3]) << 16);
      *(u32x2*)&Pl[w][fr][sub * 16 + fc * 4] = u32x2{lo, hi};
    }

#pragma unroll
    for (int dt = 0; dt < 4; ++dt)
#pragma unroll
      for (int kc = 0; kc < 2; ++kc) {
        short8 vf = *(const short8*)&Vs[cur][dt * 16 + fr][kc * 32 + fc * 8];
        short8 pb = *(const short8*)&Pl[w][fr][kc * 32 + fc * 8];
        acc[dt] = MFMA16(vf, pb, acc[dt]);
      }

    if (pref) {
      *(u16x8*)&Ks[cur ^ 1][kr0][kc0] = nk0;
      *(u16x8*)&Ks[cur ^ 1][kr1][kc1] = nk1;
      *(u16x8*)&Vs[cur ^ 1][kr0][kc0] = nv0;
      *(u16x8*)&Vs[cur ^ 1][kr1][kc1] = nv1;
    }
    __syncthreads();
  }

  float inv = 1.0f / lst;
#pragma unroll
  for (int dt = 0; dt < 4; ++dt) {
    u16x4 o = {f2bf(acc[dt][0] * inv), f2bf(acc[dt][1] * inv),
               f2bf(acc[dt][2] * inv), f2bf(acc[dt][3] * inv)};
    *(u16x4*)(Yg + ((size_t)mb * 512 + qrow) * 512 + h * 64 + dt * 16 + fc * 4) = o;
  }
}

// ---------------------------------------------------------------------------
// Projection GEMM (m97 structure): y[m][2048][512] bf16 x projT[m][512][512]
// -> out fp32.
// ---------------------------------------------------------------------------
__global__ __launch_bounds__(256) void proj_gemm_kernel(const u16* __restrict__ Y,
                                                        const u16* __restrict__ PT,
                                                        float* __restrict__ OUT) {
  __shared__ __attribute__((aligned(16))) u16 As[128 * 32];
  __shared__ __attribute__((aligned(16))) u16 Bs[128 * 32];
  int m = blockIdx.z;
  const u16* A = Y + (size_t)m * 2048 * 512;
  const u16* BT = PT + (size_t)m * 512 * 512;
  float* C = OUT + (size_t)m * 2048 * 512;
  int r0 = blockIdx.y * 128, c0 = blockIdx.x * 128;
  int t = threadIdx.x;
  int lane = t & 63, w = t >> 6;
  int wr = (w >> 1) * 64, wc = (w & 1) * 64;
  int fr = lane & 15, fc = lane >> 4;

  int u0 = w * 128 + lane;
  int u1 = w * 128 + 64 + lane;
  int ar0 = u0 >> 2, ak0 = (u0 & 3) * 8;
  int ar1 = u1 >> 2, ak1 = (u1 & 3) * 8;
  u16* lbase0 = &As[0] + (size_t)(w * 128) * 8;
  u16* lbase1 = &As[0] + (size_t)(w * 128 + 64) * 8;
  u16* lbb0 = &Bs[0] + (size_t)(w * 128) * 8;
  u16* lbb1 = &Bs[0] + (size_t)(w * 128 + 64) * 8;

  f32x4 acc[4][4];
#pragma unroll
  for (int i = 0; i < 4; ++i)
#pragma unroll
    for (int j = 0; j < 4; ++j) acc[i][j] = f32x4{0.f, 0.f, 0.f, 0.f};

  for (int kk = 0; kk < 512; kk += 32) {
    gl_lds16(A + (size_t)(r0 + ar0) * 512 + kk + ak0, lbase0);
    gl_lds16(A + (size_t)(r0 + ar1) * 512 + kk + ak1, lbase1);
    gl_lds16(BT + (size_t)(c0 + ar0) * 512 + kk + ak0, lbb0);
    gl_lds16(BT + (size_t)(c0 + ar1) * 512 + kk + ak1, lbb1);
    __syncthreads();
    short8 af[4], bf[4];
#pragma unroll
    for (int i = 0; i < 4; ++i) af[i] = *(const short8*)&As[(wr + i * 16 + fr) * 32 + fc * 8];
#pragma unroll
    for (int j = 0; j < 4; ++j) bf[j] = *(const short8*)&Bs[(wc + j * 16 + fr) * 32 + fc * 8];
#pragma unroll
    for (int i = 0; i < 4; ++i)
#pragma unroll
      for (int j = 0; j < 4; ++j) acc[i][j] = MFMA16(af[i], bf[j], acc[i][j]);
    __syncthreads();
  }
#pragma unroll
  for (int i = 0; i < 4; ++i)
#pragma unroll
    for (int j = 0; j < 4; ++j)
#pragma unroll
      for (int r = 0; r < 4; ++r) {
        int grow = r0 + wr + i * 16 + fc * 4 + r;
        int gcol = c0 + wc + j * 16 + fr;
        C[(size_t)grow * 512 + gcol] = acc[i][j][r];
      }
}

// ---------------------------------------------------------------------------
extern "C" void kernel_launch(void* const* d_in, const int* in_sizes, int n_in,
                              void* d_out, int out_size, void* d_ws, size_t ws_size,
                              hipStream_t stream) {
  const float* x = (const float*)d_in[0];      // [8][4][512][512]
  const float* wqkv = (const float*)d_in[1];   // [8][512][1536]
  const float* wproj = (const float*)d_in[2];  // [8][512][512]
  float* out = (float*)d_out;                  // [8][4][512][512]

  u16* p = (u16*)d_ws;
  u16* wqkvT = p;  p += (size_t)8 * 1536 * 512;  // bf16 [m][1536][512]
  u16* wprojT = p; p += (size_t)8 * 512 * 512;   // bf16 [m][512][512]
  u16* qb = p;     p += (size_t)8388608;         // bf16 [mb*8+h][512][64]
  u16* kb = p;     p += (size_t)8388608;         // bf16 [mb*8+h][512][64]
  u16* vtb = p;    p += (size_t)8388608;         // bf16 [mb*8+h][64][512]
  u16* xyb = p;    p += (size_t)8388608;         // bf16: xb for qkv, then yb for attn/proj

  xcast_kernel<<<2048, 256, 0, stream>>>(x, xyb, (long)8 * 4 * 512 * 512 / 8);
  wtrans_kernel<<<dim3(48, 16, 8), dim3(32, 8), 0, stream>>>(wqkv, wqkvT, 512, 1536);
  wtrans_kernel<<<dim3(16, 16, 8), dim3(32, 8), 0, stream>>>(wproj, wprojT, 512, 512);
  qkv_gemm_kernel<<<dim3(12, 16, 8), 256, 0, stream>>>(xyb, wqkvT, qb, kb, vtb);
  attn_kernel<<<2048, 256, 0, stream>>>(qb, kb, vtb, xyb);
  proj_gemm_kernel<<<dim3(4, 16, 8), 256, 0, stream>>>(xyb, wprojT, out);
}

// Round 4
// 219.941 us; speedup vs baseline: 1.4228x; 1.0036x over previous
//
#include <hip/hip_runtime.h>
#include <hip/hip_bf16.h>

// Problem: M=8, B=4, S=512, D=512, H=8, HD=64.
// Pipeline: xcast (fp32->bf16), wqkv^T+cast, wproj^T+cast
//           -> QKV GEMM (256x128 tile, dbuf global_load_lds, XCD-affine swizzle)
//           -> flash attention (transposed S/P/Y) -> proj GEMM (same structure).

typedef unsigned short u16;
typedef unsigned int u32;
typedef __attribute__((ext_vector_type(8))) short short8;        // bf16x8 MFMA frag
typedef __attribute__((ext_vector_type(4))) float f32x4;         // MFMA acc frag
typedef __attribute__((ext_vector_type(4))) unsigned short u16x4;
typedef __attribute__((ext_vector_type(8))) unsigned short u16x8;
typedef __attribute__((ext_vector_type(2))) unsigned int u32x2;

#define MFMA16(a, b, c) __builtin_amdgcn_mfma_f32_16x16x32_bf16((a), (b), (c), 0, 0, 0)

__device__ __forceinline__ u16 f2bf(float f) {
  union { __hip_bfloat16 h; u16 u; } cv;
  cv.h = __float2bfloat16(f);
  return cv.u;
}

// async global->LDS, 16B per lane; lds base must be wave-uniform.
__device__ __forceinline__ void gl_lds16(const u16* g, u16* l) {
  __builtin_amdgcn_global_load_lds(
      (const __attribute__((address_space(1))) void*)g,
      (__attribute__((address_space(3))) void*)l, 16, 0, 0);
}

// ---------------------------------------------------------------------------
// X cast: fp32 [n] -> bf16 [n], vectorized 8/thread, grid-stride.
// ---------------------------------------------------------------------------
__global__ __launch_bounds__(256) void xcast_kernel(const float* __restrict__ in,
                                                    u16* __restrict__ out, long n8) {
  long stride = (long)gridDim.x * 256;
  for (long i = blockIdx.x * 256L + threadIdx.x; i < n8; i += stride) {
    f32x4 a = *(const f32x4*)(in + i * 8);
    f32x4 b = *(const f32x4*)(in + i * 8 + 4);
    u16x8 o = {f2bf(a[0]), f2bf(a[1]), f2bf(a[2]), f2bf(a[3]),
               f2bf(b[0]), f2bf(b[1]), f2bf(b[2]), f2bf(b[3])};
    *(u16x8*)(out + i * 8) = o;
  }
}

// ---------------------------------------------------------------------------
// Weight transpose + fp32->bf16 cast: in [m][R][C] fp32 -> out [m][C][R] bf16
// ---------------------------------------------------------------------------
__global__ __launch_bounds__(256) void wtrans_kernel(const float* __restrict__ in,
                                                     u16* __restrict__ out, int R, int C) {
  __shared__ float t[32][33];
  int m = blockIdx.z;
  const float* pin = in + (size_t)m * R * C;
  u16* pout = out + (size_t)m * R * C;
  int c0 = blockIdx.x * 32, r0 = blockIdx.y * 32;
  int tx = threadIdx.x, ty = threadIdx.y;  // (32, 8)
#pragma unroll
  for (int i = 0; i < 4; ++i) {
    int r = ty + i * 8;
    t[r][tx] = pin[(size_t)(r0 + r) * C + c0 + tx];
  }
  __syncthreads();
#pragma unroll
  for (int i = 0; i < 4; ++i) {
    int r = ty + i * 8;
    pout[(size_t)(c0 + r) * R + r0 + tx] = f2bf(t[tx][r]);
  }
}

// ---------------------------------------------------------------------------
// QKV GEMM: xb[m][2048][512] bf16 x wT[m][1536][512] bf16 -> scatter q/k/vT.
// 256x128 tile, BK=32, 8 waves (4Mx2N, 64x64 each). Double-buffered
// global_load_lds staging, issue-early: stage(t+1) before compute(t), one
// barrier per K-step. Grid 768 1-D, XCD-affine: each XCD owns one m
// (A 2MB + B 1.5MB fits its 4MB L2).
// ---------------------------------------------------------------------------
__global__ __launch_bounds__(512) void qkv_gemm_kernel(const u16* __restrict__ XB,
                                                       const u16* __restrict__ WT,
                                                       u16* __restrict__ Q,
                                                       u16* __restrict__ K,
                                                       u16* __restrict__ VT) {
  __shared__ __attribute__((aligned(16))) u16 As[2][256 * 32];  // 2 x 16 KB
  __shared__ __attribute__((aligned(16))) u16 Bs[2][128 * 32];  // 2 x 8 KB
  int bid = blockIdx.x;                  // 768 blocks
  int wgid = (bid & 7) * 96 + (bid >> 3);  // XCD-affine (768 % 8 == 0: bijective)
  int m = wgid / 96;
  int rem = wgid % 96;
  int r0 = (rem / 12) * 256, c0 = (rem % 12) * 128;
  const u16* A = XB + (size_t)m * 2048 * 512;
  const u16* BT = WT + (size_t)m * 1536 * 512;
  int t = threadIdx.x;
  int lane = t & 63, w = t >> 6;          // 8 waves
  int wr = (w >> 1) * 64, wc = (w & 1) * 64;
  int fr = lane & 15, fc = lane >> 4;

  // 16B staging units: unit u -> row u>>2, k-halfword (u&3)*8.
  // A: 1024 units (256 rows); thread covers u=t and u=t+512. B: 512 units.
  int ar0 = t >> 2, ak0 = (t & 3) * 8;
  int ar1 = (t + 512) >> 2, ak1 = ((t + 512) & 3) * 8;
  u16* ldsA0[2] = {&As[0][(size_t)w * 64 * 8], &As[1][(size_t)w * 64 * 8]};
  u16* ldsA1[2] = {&As[0][(size_t)(512 + w * 64) * 8], &As[1][(size_t)(512 + w * 64) * 8]};
  u16* ldsB0[2] = {&Bs[0][(size_t)w * 64 * 8], &Bs[1][(size_t)w * 64 * 8]};

  f32x4 acc[4][4];
#pragma unroll
  for (int i = 0; i < 4; ++i)
#pragma unroll
    for (int j = 0; j < 4; ++j) acc[i][j] = f32x4{0.f, 0.f, 0.f, 0.f};

  // prologue: stage K-step 0 into buffer 0
  gl_lds16(A + (size_t)(r0 + ar0) * 512 + ak0, ldsA0[0]);
  gl_lds16(A + (size_t)(r0 + ar1) * 512 + ak1, ldsA1[0]);
  gl_lds16(BT + (size_t)(c0 + ar0) * 512 + ak0, ldsB0[0]);
  __syncthreads();

  for (int ks = 0; ks < 16; ++ks) {
    int cur = ks & 1;
    if (ks + 1 < 16) {  // issue next-tile loads; they retire under compute
      int kk = (ks + 1) * 32;
      gl_lds16(A + (size_t)(r0 + ar0) * 512 + kk + ak0, ldsA0[cur ^ 1]);
      gl_lds16(A + (size_t)(r0 + ar1) * 512 + kk + ak1, ldsA1[cur ^ 1]);
      gl_lds16(BT + (size_t)(c0 + ar0) * 512 + kk + ak0, ldsB0[cur ^ 1]);
    }
    short8 af[4], bf_[4];
#pragma unroll
    for (int i = 0; i < 4; ++i) af[i] = *(const short8*)&As[cur][(wr + i * 16 + fr) * 32 + fc * 8];
#pragma unroll
    for (int j = 0; j < 4; ++j) bf_[j] = *(const short8*)&Bs[cur][(wc + j * 16 + fr) * 32 + fc * 8];
#pragma unroll
    for (int i = 0; i < 4; ++i)
#pragma unroll
      for (int j = 0; j < 4; ++j) acc[i][j] = MFMA16(af[i], bf_[j], acc[i][j]);
    __syncthreads();  // drains prefetch vmcnt + compute lgkm; 1 barrier/K-step
  }

  int seg = c0 >> 9;  // uniform per block: 0=q, 1=k, 2=v
#pragma unroll
  for (int i = 0; i < 4; ++i) {
#pragma unroll
    for (int j = 0; j < 4; ++j) {
#pragma unroll
      for (int r = 0; r < 4; ++r) {
        int grow = r0 + wr + i * 16 + fc * 4 + r;
        int gcol = c0 + wc + j * 16 + fr;
        int b = grow >> 9, s = grow & 511;
        int cc = gcol & 511;
        int hh = cc >> 6, hd = cc & 63;
        size_t headoff = (size_t)((m * 4 + b) * 8 + hh) * 32768;  // S*HD
        u16 val = f2bf(acc[i][j][r]);
        if (seg == 0)      Q[headoff + s * 64 + hd] = val;
        else if (seg == 1) K[headoff + s * 64 + hd] = val;
        else               VT[headoff + hd * 512 + s] = val;
      }
    }
  }
}

// ---------------------------------------------------------------------------
// Flash attention, transposed pipeline (unchanged from R2).
// ---------------------------------------------------------------------------
__global__ __launch_bounds__(256) void attn_kernel(const u16* __restrict__ Qg,
                                                   const u16* __restrict__ Kg,
                                                   const u16* __restrict__ VTg,
                                                   u16* __restrict__ Yg) {
  __shared__ u16 Ks[2][64][72];
  __shared__ u16 Vs[2][64][72];
  __shared__ u16 Pl[4][16][72];
  int bid = blockIdx.x;
  int qt = bid >> 8;
  int g = bid & 255;
  int h = g & 7, mb = g >> 3;
  int t = threadIdx.x, lane = t & 63, w = t >> 6;
  int fr = lane & 15, fc = lane >> 4;
  size_t hoff = ((size_t)mb * 8 + h) * 32768;
  const u16* Q = Qg + hoff;
  const u16* K = Kg + hoff;
  const u16* V = VTg + hoff;  // [hd][s]
  int qrow = qt * 64 + w * 16 + fr;
  const float SC = 0.125f * 1.44269504088896340736f;

  short8 qf0 = *(const short8*)(Q + (size_t)qrow * 64 + fc * 8);
  short8 qf1 = *(const short8*)(Q + (size_t)qrow * 64 + 32 + fc * 8);

  f32x4 acc[4];
#pragma unroll
  for (int d = 0; d < 4; ++d) acc[d] = f32x4{0.f, 0.f, 0.f, 0.f};
  float mst = -1e30f, lst = 0.f;

  int u0 = 2 * t, u1 = 2 * t + 1;
  int kr0 = u0 >> 3, kc0 = (u0 & 7) * 8;
  int kr1 = u1 >> 3, kc1 = (u1 & 7) * 8;

  {
    u16x8 a0 = *(const u16x8*)(K + (size_t)kr0 * 64 + kc0);
    u16x8 a1 = *(const u16x8*)(K + (size_t)kr1 * 64 + kc1);
    u16x8 b0 = *(const u16x8*)(V + (size_t)kr0 * 512 + kc0);
    u16x8 b1 = *(const u16x8*)(V + (size_t)kr1 * 512 + kc1);
    *(u16x8*)&Ks[0][kr0][kc0] = a0;
    *(u16x8*)&Ks[0][kr1][kc1] = a1;
    *(u16x8*)&Vs[0][kr0][kc0] = b0;
    *(u16x8*)&Vs[0][kr1][kc1] = b1;
  }
  __syncthreads();

  for (int kt = 0; kt <= qt; ++kt) {
    int cur = kt & 1;
    bool pref = kt < qt;
    u16x8 nk0, nk1, nv0, nv1;
    if (pref) {
      int kbn = (kt + 1) * 64;
      nk0 = *(const u16x8*)(K + (size_t)(kbn + kr0) * 64 + kc0);
      nk1 = *(const u16x8*)(K + (size_t)(kbn + kr1) * 64 + kc1);
      nv0 = *(const u16x8*)(V + (size_t)kr0 * 512 + kbn + kc0);
      nv1 = *(const u16x8*)(V + (size_t)kr1 * 512 + kbn + kc1);
    }

    f32x4 st[4];
#pragma unroll
    for (int sub = 0; sub < 4; ++sub) {
      short8 kf0 = *(const short8*)&Ks[cur][sub * 16 + fr][fc * 8];
      short8 kf1 = *(const short8*)&Ks[cur][sub * 16 + fr][32 + fc * 8];
      f32x4 z = f32x4{0.f, 0.f, 0.f, 0.f};
      z = MFMA16(kf0, qf0, z);
      st[sub] = MFMA16(kf1, qf1, z);
    }

    float p[4][4];
    float mt = -3e30f;
    bool diag = (kt == qt);
    int qloc = w * 16 + fr;
#pragma unroll
    for (int sub = 0; sub < 4; ++sub)
#pragma unroll
      for (int r = 0; r < 4; ++r) {
        float v = st[sub][r] * SC;
        if (diag && (sub * 16 + fc * 4 + r) > qloc) v = -1e30f;
        p[sub][r] = v;
        mt = fmaxf(mt, v);
      }
    mt = fmaxf(mt, __shfl_xor(mt, 16));
    mt = fmaxf(mt, __shfl_xor(mt, 32));
    float mn = fmaxf(mst, mt);
    float al = __builtin_amdgcn_exp2f(mst - mn);
    mst = mn;
    float rs = 0.f;
#pragma unroll
    for (int sub = 0; sub < 4; ++sub)
#pragma unroll
      for (int r = 0; r < 4; ++r) {
        float e = __builtin_amdgcn_exp2f(p[sub][r] - mn);
        p[sub][r] = e;
        rs += e;
      }
    rs += __shfl_xor(rs, 16);
    rs += __shfl_xor(rs, 32);
    lst = lst * al + rs;
#pragma unroll
    for (int d = 0; d < 4; ++d) acc[d] *= al;

#pragma unroll
    for (int sub = 0; sub < 4; ++sub) {
      u32 lo = (u32)f2bf(p[sub][0]) | ((u32)f2bf(p[sub][1]) << 16);
      u32 hi = (u32)f2bf(p[sub][2]) | ((u32)f2bf(p[sub][3]) << 16);
      *(u32x2*)&Pl[w][fr][sub * 16 + fc * 4] = u32x2{lo, hi};
    }

#pragma unroll
    for (int dt = 0; dt < 4; ++dt)
#pragma unroll
      for (int kc = 0; kc < 2; ++kc) {
        short8 vf = *(const short8*)&Vs[cur][dt * 16 + fr][kc * 32 + fc * 8];
        short8 pb = *(const short8*)&Pl[w][fr][kc * 32 + fc * 8];
        acc[dt] = MFMA16(vf, pb, acc[dt]);
      }

    if (pref) {
      *(u16x8*)&Ks[cur ^ 1][kr0][kc0] = nk0;
      *(u16x8*)&Ks[cur ^ 1][kr1][kc1] = nk1;
      *(u16x8*)&Vs[cur ^ 1][kr0][kc0] = nv0;
      *(u16x8*)&Vs[cur ^ 1][kr1][kc1] = nv1;
    }
    __syncthreads();
  }

  float inv = 1.0f / lst;
#pragma unroll
  for (int dt = 0; dt < 4; ++dt) {
    u16x4 o = {f2bf(acc[dt][0] * inv), f2bf(acc[dt][1] * inv),
               f2bf(acc[dt][2] * inv), f2bf(acc[dt][3] * inv)};
    *(u16x4*)(Yg + ((size_t)mb * 512 + qrow) * 512 + h * 64 + dt * 16 + fc * 4) = o;
  }
}

// ---------------------------------------------------------------------------
// Projection GEMM: y[m][2048][512] bf16 x projT[m][512][512] -> out fp32.
// Same 256x128 dbuf structure; grid 256 = 8 XCDs x 32 (one m per XCD).
// ---------------------------------------------------------------------------
__global__ __launch_bounds__(512) void proj_gemm_kernel(const u16* __restrict__ Y,
                                                        const u16* __restrict__ PT,
                                                        float* __restrict__ OUT) {
  __shared__ __attribute__((aligned(16))) u16 As[2][256 * 32];
  __shared__ __attribute__((aligned(16))) u16 Bs[2][128 * 32];
  int bid = blockIdx.x;                    // 256 blocks
  int wgid = (bid & 7) * 32 + (bid >> 3);  // XCD-affine
  int m = wgid / 32;
  int rem = wgid % 32;
  int r0 = (rem / 4) * 256, c0 = (rem % 4) * 128;
  const u16* A = Y + (size_t)m * 2048 * 512;
  const u16* BT = PT + (size_t)m * 512 * 512;
  float* C = OUT + (size_t)m * 2048 * 512;
  int t = threadIdx.x;
  int lane = t & 63, w = t >> 6;
  int wr = (w >> 1) * 64, wc = (w & 1) * 64;
  int fr = lane & 15, fc = lane >> 4;

  int ar0 = t >> 2, ak0 = (t & 3) * 8;
  int ar1 = (t + 512) >> 2, ak1 = ((t + 512) & 3) * 8;
  u16* ldsA0[2] = {&As[0][(size_t)w * 64 * 8], &As[1][(size_t)w * 64 * 8]};
  u16* ldsA1[2] = {&As[0][(size_t)(512 + w * 64) * 8], &As[1][(size_t)(512 + w * 64) * 8]};
  u16* ldsB0[2] = {&Bs[0][(size_t)w * 64 * 8], &Bs[1][(size_t)w * 64 * 8]};

  f32x4 acc[4][4];
#pragma unroll
  for (int i = 0; i < 4; ++i)
#pragma unroll
    for (int j = 0; j < 4; ++j) acc[i][j] = f32x4{0.f, 0.f, 0.f, 0.f};

  gl_lds16(A + (size_t)(r0 + ar0) * 512 + ak0, ldsA0[0]);
  gl_lds16(A + (size_t)(r0 + ar1) * 512 + ak1, ldsA1[0]);
  gl_lds16(BT + (size_t)(c0 + ar0) * 512 + ak0, ldsB0[0]);
  __syncthreads();

  for (int ks = 0; ks < 16; ++ks) {
    int cur = ks & 1;
    if (ks + 1 < 16) {
      int kk = (ks + 1) * 32;
      gl_lds16(A + (size_t)(r0 + ar0) * 512 + kk + ak0, ldsA0[cur ^ 1]);
      gl_lds16(A + (size_t)(r0 + ar1) * 512 + kk + ak1, ldsA1[cur ^ 1]);
      gl_lds16(BT + (size_t)(c0 + ar0) * 512 + kk + ak0, ldsB0[cur ^ 1]);
    }
    short8 af[4], bf_[4];
#pragma unroll
    for (int i = 0; i < 4; ++i) af[i] = *(const short8*)&As[cur][(wr + i * 16 + fr) * 32 + fc * 8];
#pragma unroll
    for (int j = 0; j < 4; ++j) bf_[j] = *(const short8*)&Bs[cur][(wc + j * 16 + fr) * 32 + fc * 8];
#pragma unroll
    for (int i = 0; i < 4; ++i)
#pragma unroll
      for (int j = 0; j < 4; ++j) acc[i][j] = MFMA16(af[i], bf_[j], acc[i][j]);
    __syncthreads();
  }
#pragma unroll
  for (int i = 0; i < 4; ++i)
#pragma unroll
    for (int j = 0; j < 4; ++j)
#pragma unroll
      for (int r = 0; r < 4; ++r) {
        int grow = r0 + wr + i * 16 + fc * 4 + r;
        int gcol = c0 + wc + j * 16 + fr;
        C[(size_t)grow * 512 + gcol] = acc[i][j][r];
      }
}

// ---------------------------------------------------------------------------
extern "C" void kernel_launch(void* const* d_in, const int* in_sizes, int n_in,
                              void* d_out, int out_size, void* d_ws, size_t ws_size,
                              hipStream_t stream) {
  const float* x = (const float*)d_in[0];      // [8][4][512][512]
  const float* wqkv = (const float*)d_in[1];   // [8][512][1536]
  const float* wproj = (const float*)d_in[2];  // [8][512][512]
  float* out = (float*)d_out;                  // [8][4][512][512]

  u16* p = (u16*)d_ws;
  u16* wqkvT = p;  p += (size_t)8 * 1536 * 512;  // bf16 [m][1536][512]
  u16* wprojT = p; p += (size_t)8 * 512 * 512;   // bf16 [m][512][512]
  u16* qb = p;     p += (size_t)8388608;         // bf16 [mb*8+h][512][64]
  u16* kb = p;     p += (size_t)8388608;         // bf16 [mb*8+h][512][64]
  u16* vtb = p;    p += (size_t)8388608;         // bf16 [mb*8+h][64][512]
  u16* xyb = p;    p += (size_t)8388608;         // bf16: xb for qkv, then yb

  xcast_kernel<<<2048, 256, 0, stream>>>(x, xyb, (long)8 * 4 * 512 * 512 / 8);
  wtrans_kernel<<<dim3(48, 16, 8), dim3(32, 8), 0, stream>>>(wqkv, wqkvT, 512, 1536);
  wtrans_kernel<<<dim3(16, 16, 8), dim3(32, 8), 0, stream>>>(wproj, wprojT, 512, 512);
  qkv_gemm_kernel<<<768, 512, 0, stream>>>(xyb, wqkvT, qb, kb, vtb);
  attn_kernel<<<2048, 256, 0, stream>>>(qb, kb, vtb, xyb);
  proj_gemm_kernel<<<256, 512, 0, stream>>>(xyb, wprojT, out);
}

// Round 5
// 191.542 us; speedup vs baseline: 1.6338x; 1.1483x over previous
//
#include <hip/hip_runtime.h>
#include <hip/hip_bf16.h>

// Problem: M=8, B=4, S=512, D=512, H=8, HD=64.
// Pipeline: xcast (fp32->bf16), wqkv^T+cast, wproj^T+cast
//           -> QKV GEMM (128x128 tile, 3-buffer depth-2 counted-vmcnt pipeline,
//              T2 read-swizzle, XCD-affine) -> flash attention -> proj GEMM.

typedef unsigned short u16;
typedef unsigned int u32;
typedef __attribute__((ext_vector_type(8))) short short8;        // bf16x8 MFMA frag
typedef __attribute__((ext_vector_type(4))) float f32x4;         // MFMA acc frag
typedef __attribute__((ext_vector_type(4))) unsigned short u16x4;
typedef __attribute__((ext_vector_type(8))) unsigned short u16x8;
typedef __attribute__((ext_vector_type(2))) unsigned int u32x2;

#define MFMA16(a, b, c) __builtin_amdgcn_mfma_f32_16x16x32_bf16((a), (b), (c), 0, 0, 0)

__device__ __forceinline__ u16 f2bf(float f) {
  union { __hip_bfloat16 h; u16 u; } cv;
  cv.h = __float2bfloat16(f);
  return cv.u;
}

// async global->LDS, 16B per lane; lds base must be wave-uniform.
__device__ __forceinline__ void gl_lds16(const u16* g, u16* l) {
  __builtin_amdgcn_global_load_lds(
      (const __attribute__((address_space(1))) void*)g,
      (__attribute__((address_space(3))) void*)l, 16, 0, 0);
}

// ---------------------------------------------------------------------------
// X cast: fp32 [n] -> bf16 [n], vectorized 8/thread, grid-stride.
// ---------------------------------------------------------------------------
__global__ __launch_bounds__(256) void xcast_kernel(const float* __restrict__ in,
                                                    u16* __restrict__ out, long n8) {
  long stride = (long)gridDim.x * 256;
  for (long i = blockIdx.x * 256L + threadIdx.x; i < n8; i += stride) {
    f32x4 a = *(const f32x4*)(in + i * 8);
    f32x4 b = *(const f32x4*)(in + i * 8 + 4);
    u16x8 o = {f2bf(a[0]), f2bf(a[1]), f2bf(a[2]), f2bf(a[3]),
               f2bf(b[0]), f2bf(b[1]), f2bf(b[2]), f2bf(b[3])};
    *(u16x8*)(out + i * 8) = o;
  }
}

// ---------------------------------------------------------------------------
// Weight transpose + fp32->bf16 cast: in [m][R][C] fp32 -> out [m][C][R] bf16
// ---------------------------------------------------------------------------
__global__ __launch_bounds__(256) void wtrans_kernel(const float* __restrict__ in,
                                                     u16* __restrict__ out, int R, int C) {
  __shared__ float t[32][33];
  int m = blockIdx.z;
  const float* pin = in + (size_t)m * R * C;
  u16* pout = out + (size_t)m * R * C;
  int c0 = blockIdx.x * 32, r0 = blockIdx.y * 32;
  int tx = threadIdx.x, ty = threadIdx.y;  // (32, 8)
#pragma unroll
  for (int i = 0; i < 4; ++i) {
    int r = ty + i * 8;
    t[r][tx] = pin[(size_t)(r0 + r) * C + c0 + tx];
  }
  __syncthreads();
#pragma unroll
  for (int i = 0; i < 4; ++i) {
    int r = ty + i * 8;
    pout[(size_t)(c0 + r) * R + r0 + tx] = f2bf(t[tx][r]);
  }
}

// ---------------------------------------------------------------------------
// QKV GEMM: xb[m][2048][512] bf16 x wT[m][1536][512] bf16 -> scatter q/k/vT.
// 128x128 tile, BK=32, 4 waves. 3 LDS buffers, depth-2 prefetch with counted
// s_waitcnt vmcnt(4) (loads never drained to 0 in the loop), one s_barrier
// per K-step. LDS tiles linear for global_load_lds; reads use slot-XOR
// swizzle (slot ^= (row>>1)&3) with pre-swizzled global source (rule 21):
// breaks the 8-way bank conflict on ds_read_b128 down to 2-way (free).
// Grid 1536 1-D, XCD-affine: each XCD owns one m (inputs fit its 4MB L2).
// ---------------------------------------------------------------------------
__global__ __launch_bounds__(256) void qkv_gemm_kernel(const u16* __restrict__ XB,
                                                       const u16* __restrict__ WT,
                                                       u16* __restrict__ Q,
                                                       u16* __restrict__ K,
                                                       u16* __restrict__ VT) {
  __shared__ __attribute__((aligned(16))) u16 As[3][128 * 32];  // 3 x 8 KB
  __shared__ __attribute__((aligned(16))) u16 Bs[3][128 * 32];  // 3 x 8 KB
  int bid = blockIdx.x;                     // 1536 blocks
  int wgid = (bid & 7) * 192 + (bid >> 3);  // XCD-affine (1536 % 8 == 0)
  int m = wgid / 192;
  int rem = wgid % 192;
  int r0 = (rem / 12) * 128, c0 = (rem % 12) * 128;
  const u16* A = XB + (size_t)m * 2048 * 512;
  const u16* BT = WT + (size_t)m * 1536 * 512;
  int t = threadIdx.x;
  int lane = t & 63, w = t >> 6;            // 4 waves
  int wr = (w >> 1) * 64, wc = (w & 1) * 64;
  int fr = lane & 15, fc = lane >> 4;

  // staging: unit u (16B) -> row u>>2, lds slot u&3; global chunk = slot ^ ((row>>1)&3).
  // thread covers units t and t+256; wave w's units are [w*64,w*64+64) and +256 (linear dest).
  int rA0 = t >> 2, cA0 = t & 3, sA0 = cA0 ^ ((rA0 >> 1) & 3);
  int rA1 = (t + 256) >> 2, cA1 = t & 3, sA1 = cA1 ^ ((rA1 >> 1) & 3);

  f32x4 acc[4][4];
#pragma unroll
  for (int i = 0; i < 4; ++i)
#pragma unroll
    for (int j = 0; j < 4; ++j) acc[i][j] = f32x4{0.f, 0.f, 0.f, 0.f};

#define QKV_STAGE(tile)                                                          \
  {                                                                              \
    int kk_ = (tile) * 32;                                                       \
    int b_ = (tile) % 3;                                                         \
    gl_lds16(A + (size_t)(r0 + rA0) * 512 + kk_ + sA0 * 8, &As[b_][w * 512]);    \
    gl_lds16(A + (size_t)(r0 + rA1) * 512 + kk_ + sA1 * 8, &As[b_][2048 + w * 512]); \
    gl_lds16(BT + (size_t)(c0 + rA0) * 512 + kk_ + sA0 * 8, &Bs[b_][w * 512]);   \
    gl_lds16(BT + (size_t)(c0 + rA1) * 512 + kk_ + sA1 * 8, &Bs[b_][2048 + w * 512]); \
  }

#define QKV_COMPUTE(tile)                                                        \
  {                                                                              \
    int b_ = (tile) % 3;                                                         \
    short8 af[4], bf_[4];                                                        \
    _Pragma("unroll") for (int i = 0; i < 4; ++i) {                              \
      int row = wr + i * 16 + fr;                                                \
      int sl = fc ^ ((row >> 1) & 3);                                            \
      af[i] = *(const short8*)&As[b_][row * 32 + sl * 8];                        \
    }                                                                            \
    _Pragma("unroll") for (int j = 0; j < 4; ++j) {                              \
      int row = wc + j * 16 + fr;                                                \
      int sl = fc ^ ((row >> 1) & 3);                                            \
      bf_[j] = *(const short8*)&Bs[b_][row * 32 + sl * 8];                       \
    }                                                                            \
    _Pragma("unroll") for (int i = 0; i < 4; ++i)                                \
      _Pragma("unroll") for (int j = 0; j < 4; ++j)                              \
        acc[i][j] = MFMA16(af[i], bf_[j], acc[i][j]);                            \
  }

  QKV_STAGE(0);
  QKV_STAGE(1);
  for (int ks = 0; ks < 14; ++ks) {
    asm volatile("s_waitcnt vmcnt(4)" ::: "memory");  // tile ks done; ks+1 in flight
    __builtin_amdgcn_sched_barrier(0);
    __builtin_amdgcn_s_barrier();
    QKV_STAGE(ks + 2);   // into buf[(ks+2)%3] == buf[(ks-1)%3], fully consumed
    QKV_COMPUTE(ks);
    __builtin_amdgcn_sched_barrier(0);  // pin MFMAs (and lgkm waits) before next barrier
  }
  asm volatile("s_waitcnt vmcnt(0)" ::: "memory");
  __builtin_amdgcn_sched_barrier(0);
  __builtin_amdgcn_s_barrier();
  QKV_COMPUTE(14);
  QKV_COMPUTE(15);

  int seg = c0 >> 9;  // uniform per block: 0=q, 1=k, 2=v
  if (seg == 2) {
    // VT[hd][s]: the 4 acc values per frag are s-consecutive -> packed 8B stores
#pragma unroll
    for (int i = 0; i < 4; ++i)
#pragma unroll
      for (int j = 0; j < 4; ++j) {
        int s0 = r0 + wr + i * 16 + fc * 4;
        int gcol = c0 + wc + j * 16 + fr;
        int cc = gcol & 511;
        int hh = cc >> 6, hd = cc & 63;
        int b = s0 >> 9, s = s0 & 511;
        size_t headoff = (size_t)((m * 4 + b) * 8 + hh) * 32768;
        u16x4 pk = {f2bf(acc[i][j][0]), f2bf(acc[i][j][1]),
                    f2bf(acc[i][j][2]), f2bf(acc[i][j][3])};
        *(u16x4*)(VT + headoff + (size_t)hd * 512 + s) = pk;
      }
  } else {
#pragma unroll
    for (int i = 0; i < 4; ++i)
#pragma unroll
      for (int j = 0; j < 4; ++j)
#pragma unroll
        for (int r = 0; r < 4; ++r) {
          int grow = r0 + wr + i * 16 + fc * 4 + r;
          int gcol = c0 + wc + j * 16 + fr;
          int b = grow >> 9, s = grow & 511;
          int cc = gcol & 511;
          int hh = cc >> 6, hd = cc & 63;
          size_t headoff = (size_t)((m * 4 + b) * 8 + hh) * 32768;
          u16 val = f2bf(acc[i][j][r]);
          if (seg == 0) Q[headoff + s * 64 + hd] = val;
          else          K[headoff + s * 64 + hd] = val;
        }
  }
}

// ---------------------------------------------------------------------------
// Flash attention, transposed pipeline (unchanged).
// ---------------------------------------------------------------------------
__global__ __launch_bounds__(256) void attn_kernel(const u16* __restrict__ Qg,
                                                   const u16* __restrict__ Kg,
                                                   const u16* __restrict__ VTg,
                                                   u16* __restrict__ Yg) {
  __shared__ u16 Ks[2][64][72];
  __shared__ u16 Vs[2][64][72];
  __shared__ u16 Pl[4][16][72];
  int bid = blockIdx.x;
  int qt = bid >> 8;
  int g = bid & 255;
  int h = g & 7, mb = g >> 3;
  int t = threadIdx.x, lane = t & 63, w = t >> 6;
  int fr = lane & 15, fc = lane >> 4;
  size_t hoff = ((size_t)mb * 8 + h) * 32768;
  const u16* Q = Qg + hoff;
  const u16* K = Kg + hoff;
  const u16* V = VTg + hoff;  // [hd][s]
  int qrow = qt * 64 + w * 16 + fr;
  const float SC = 0.125f * 1.44269504088896340736f;

  short8 qf0 = *(const short8*)(Q + (size_t)qrow * 64 + fc * 8);
  short8 qf1 = *(const short8*)(Q + (size_t)qrow * 64 + 32 + fc * 8);

  f32x4 acc[4];
#pragma unroll
  for (int d = 0; d < 4; ++d) acc[d] = f32x4{0.f, 0.f, 0.f, 0.f};
  float mst = -1e30f, lst = 0.f;

  int u0 = 2 * t, u1 = 2 * t + 1;
  int kr0 = u0 >> 3, kc0 = (u0 & 7) * 8;
  int kr1 = u1 >> 3, kc1 = (u1 & 7) * 8;

  {
    u16x8 a0 = *(const u16x8*)(K + (size_t)kr0 * 64 + kc0);
    u16x8 a1 = *(const u16x8*)(K + (size_t)kr1 * 64 + kc1);
    u16x8 b0 = *(const u16x8*)(V + (size_t)kr0 * 512 + kc0);
    u16x8 b1 = *(const u16x8*)(V + (size_t)kr1 * 512 + kc1);
    *(u16x8*)&Ks[0][kr0][kc0] = a0;
    *(u16x8*)&Ks[0][kr1][kc1] = a1;
    *(u16x8*)&Vs[0][kr0][kc0] = b0;
    *(u16x8*)&Vs[0][kr1][kc1] = b1;
  }
  __syncthreads();

  for (int kt = 0; kt <= qt; ++kt) {
    int cur = kt & 1;
    bool pref = kt < qt;
    u16x8 nk0, nk1, nv0, nv1;
    if (pref) {
      int kbn = (kt + 1) * 64;
      nk0 = *(const u16x8*)(K + (size_t)(kbn + kr0) * 64 + kc0);
      nk1 = *(const u16x8*)(K + (size_t)(kbn + kr1) * 64 + kc1);
      nv0 = *(const u16x8*)(V + (size_t)kr0 * 512 + kbn + kc0);
      nv1 = *(const u16x8*)(V + (size_t)kr1 * 512 + kbn + kc1);
    }

    f32x4 st[4];
#pragma unroll
    for (int sub = 0; sub < 4; ++sub) {
      short8 kf0 = *(const short8*)&Ks[cur][sub * 16 + fr][fc * 8];
      short8 kf1 = *(const short8*)&Ks[cur][sub * 16 + fr][32 + fc * 8];
      f32x4 z = f32x4{0.f, 0.f, 0.f, 0.f};
      z = MFMA16(kf0, qf0, z);
      st[sub] = MFMA16(kf1, qf1, z);
    }

    float p[4][4];
    float mt = -3e30f;
    bool diag = (kt == qt);
    int qloc = w * 16 + fr;
#pragma unroll
    for (int sub = 0; sub < 4; ++sub)
#pragma unroll
      for (int r = 0; r < 4; ++r) {
        float v = st[sub][r] * SC;
        if (diag && (sub * 16 + fc * 4 + r) > qloc) v = -1e30f;
        p[sub][r] = v;
        mt = fmaxf(mt, v);
      }
    mt = fmaxf(mt, __shfl_xor(mt, 16));
    mt = fmaxf(mt, __shfl_xor(mt, 32));
    float mn = fmaxf(mst, mt);
    float al = __builtin_amdgcn_exp2f(mst - mn);
    mst = mn;
    float rs = 0.f;
#pragma unroll
    for (int sub = 0; sub < 4; ++sub)
#pragma unroll
      for (int r = 0; r < 4; ++r) {
        float e = __builtin_amdgcn_exp2f(p[sub][r] - mn);
        p[sub][r] = e;
        rs += e;
      }
    rs += __shfl_xor(rs, 16);
    rs += __shfl_xor(rs, 32);
    lst = lst * al + rs;
#pragma unroll
    for (int d = 0; d < 4; ++d) acc[d] *= al;

#pragma unroll
    for (int sub = 0; sub < 4; ++sub) {
      u32 lo = (u32)f2bf(p[sub][0]) | ((u32)f2bf(p[sub][1]) << 16);
      u32 hi = (u32)f2bf(p[sub][2]) | ((u32)f2bf(p[sub][3]) << 16);
      *(u32x2*)&Pl[w][fr][sub * 16 + fc * 4] = u32x2{lo, hi};
    }

#pragma unroll
    for (int dt = 0; dt < 4; ++dt)
#pragma unroll
      for (int kc = 0; kc < 2; ++kc) {
        short8 vf = *(const short8*)&Vs[cur][dt * 16 + fr][kc * 32 + fc * 8];
        short8 pb = *(const short8*)&Pl[w][fr][kc * 32 + fc * 8];
        acc[dt] = MFMA16(vf, pb, acc[dt]);
      }

    if (pref) {
      *(u16x8*)&Ks[cur ^ 1][kr0][kc0] = nk0;
      *(u16x8*)&Ks[cur ^ 1][kr1][kc1] = nk1;
      *(u16x8*)&Vs[cur ^ 1][kr0][kc0] = nv0;
      *(u16x8*)&Vs[cur ^ 1][kr1][kc1] = nv1;
    }
    __syncthreads();
  }

  float inv = 1.0f / lst;
#pragma unroll
  for (int dt = 0; dt < 4; ++dt) {
    u16x4 o = {f2bf(acc[dt][0] * inv), f2bf(acc[dt][1] * inv),
               f2bf(acc[dt][2] * inv), f2bf(acc[dt][3] * inv)};
    *(u16x4*)(Yg + ((size_t)mb * 512 + qrow) * 512 + h * 64 + dt * 16 + fc * 4) = o;
  }
}

// ---------------------------------------------------------------------------
// Projection GEMM: y[m][2048][512] bf16 x projT[m][512][512] -> out fp32.
// Same 3-buffer depth-2 counted-vmcnt structure. Grid 512 = 8 XCDs x 64.
// ---------------------------------------------------------------------------
__global__ __launch_bounds__(256) void proj_gemm_kernel(const u16* __restrict__ Y,
                                                        const u16* __restrict__ PT,
                                                        float* __restrict__ OUT) {
  __shared__ __attribute__((aligned(16))) u16 As[3][128 * 32];
  __shared__ __attribute__((aligned(16))) u16 Bs[3][128 * 32];
  int bid = blockIdx.x;                    // 512 blocks
  int wgid = (bid & 7) * 64 + (bid >> 3);  // XCD-affine
  int m = wgid / 64;
  int rem = wgid % 64;
  int r0 = (rem / 4) * 128, c0 = (rem % 4) * 128;
  const u16* A = Y + (size_t)m * 2048 * 512;
  const u16* BT = PT + (size_t)m * 512 * 512;
  float* C = OUT + (size_t)m * 2048 * 512;
  int t = threadIdx.x;
  int lane = t & 63, w = t >> 6;
  int wr = (w >> 1) * 64, wc = (w & 1) * 64;
  int fr = lane & 15, fc = lane >> 4;

  int rA0 = t >> 2, sA0 = (t & 3) ^ ((rA0 >> 1) & 3);
  int rA1 = (t + 256) >> 2, sA1 = (t & 3) ^ ((rA1 >> 1) & 3);

  f32x4 acc[4][4];
#pragma unroll
  for (int i = 0; i < 4; ++i)
#pragma unroll
    for (int j = 0; j < 4; ++j) acc[i][j] = f32x4{0.f, 0.f, 0.f, 0.f};

#define PROJ_STAGE(tile)                                                         \
  {                                                                              \
    int kk_ = (tile) * 32;                                                       \
    int b_ = (tile) % 3;                                                         \
    gl_lds16(A + (size_t)(r0 + rA0) * 512 + kk_ + sA0 * 8, &As[b_][w * 512]);    \
    gl_lds16(A + (size_t)(r0 + rA1) * 512 + kk_ + sA1 * 8, &As[b_][2048 + w * 512]); \
    gl_lds16(BT + (size_t)(c0 + rA0) * 512 + kk_ + sA0 * 8, &Bs[b_][w * 512]);   \
    gl_lds16(BT + (size_t)(c0 + rA1) * 512 + kk_ + sA1 * 8, &Bs[b_][2048 + w * 512]); \
  }

#define PROJ_COMPUTE(tile)                                                       \
  {                                                                              \
    int b_ = (tile) % 3;                                                         \
    short8 af[4], bf_[4];                                                        \
    _Pragma("unroll") for (int i = 0; i < 4; ++i) {                              \
      int row = wr + i * 16 + fr;                                                \
      int sl = fc ^ ((row >> 1) & 3);                                            \
      af[i] = *(const short8*)&As[b_][row * 32 + sl * 8];                        \
    }                                                                            \
    _Pragma("unroll") for (int j = 0; j < 4; ++j) {                              \
      int row = wc + j * 16 + fr;                                                \
      int sl = fc ^ ((row >> 1) & 3);                                            \
      bf_[j] = *(const short8*)&Bs[b_][row * 32 + sl * 8];                       \
    }                                                                            \
    _Pragma("unroll") for (int i = 0; i < 4; ++i)                                \
      _Pragma("unroll") for (int j = 0; j < 4; ++j)                              \
        acc[i][j] = MFMA16(af[i], bf_[j], acc[i][j]);                            \
  }

  PROJ_STAGE(0);
  PROJ_STAGE(1);
  for (int ks = 0; ks < 14; ++ks) {
    asm volatile("s_waitcnt vmcnt(4)" ::: "memory");
    __builtin_amdgcn_sched_barrier(0);
    __builtin_amdgcn_s_barrier();
    PROJ_STAGE(ks + 2);
    PROJ_COMPUTE(ks);
    __builtin_amdgcn_sched_barrier(0);
  }
  asm volatile("s_waitcnt vmcnt(0)" ::: "memory");
  __builtin_amdgcn_sched_barrier(0);
  __builtin_amdgcn_s_barrier();
  PROJ_COMPUTE(14);
  PROJ_COMPUTE(15);

#pragma unroll
  for (int i = 0; i < 4; ++i)
#pragma unroll
    for (int j = 0; j < 4; ++j)
#pragma unroll
      for (int r = 0; r < 4; ++r) {
        int grow = r0 + wr + i * 16 + fc * 4 + r;
        int gcol = c0 + wc + j * 16 + fr;
        C[(size_t)grow * 512 + gcol] = acc[i][j][r];
      }
}

// ---------------------------------------------------------------------------
extern "C" void kernel_launch(void* const* d_in, const int* in_sizes, int n_in,
                              void* d_out, int out_size, void* d_ws, size_t ws_size,
                              hipStream_t stream) {
  const float* x = (const float*)d_in[0];      // [8][4][512][512]
  const float* wqkv = (const float*)d_in[1];   // [8][512][1536]
  const float* wproj = (const float*)d_in[2];  // [8][512][512]
  float* out = (float*)d_out;                  // [8][4][512][512]

  u16* p = (u16*)d_ws;
  u16* wqkvT = p;  p += (size_t)8 * 1536 * 512;  // bf16 [m][1536][512]
  u16* wprojT = p; p += (size_t)8 * 512 * 512;   // bf16 [m][512][512]
  u16* qb = p;     p += (size_t)8388608;         // bf16 [mb*8+h][512][64]
  u16* kb = p;     p += (size_t)8388608;         // bf16 [mb*8+h][512][64]
  u16* vtb = p;    p += (size_t)8388608;         // bf16 [mb*8+h][64][512]
  u16* xyb = p;    p += (size_t)8388608;         // bf16: xb for qkv, then yb

  xcast_kernel<<<2048, 256, 0, stream>>>(x, xyb, (long)8 * 4 * 512 * 512 / 8);
  wtrans_kernel<<<dim3(48, 16, 8), dim3(32, 8), 0, stream>>>(wqkv, wqkvT, 512, 1536);
  wtrans_kernel<<<dim3(16, 16, 8), dim3(32, 8), 0, stream>>>(wproj, wprojT, 512, 512);
  qkv_gemm_kernel<<<1536, 256, 0, stream>>>(xyb, wqkvT, qb, kb, vtb);
  attn_kernel<<<2048, 256, 0, stream>>>(qb, kb, vtb, xyb);
  proj_gemm_kernel<<<512, 256, 0, stream>>>(xyb, wprojT, out);
}

// Round 7
// 190.389 us; speedup vs baseline: 1.6437x; 1.0061x over previous
//
#include <hip/hip_runtime.h>
#include <hip/hip_bf16.h>

// Problem: M=8, B=4, S=512, D=512, H=8, HD=64.
// Pipeline: xcast, wtrans x2 -> QKV GEMM (256x128, 3-buf counted-vmcnt, swizzle)
//           -> paired-tile flash attention (gl_lds K/V, swizzled) -> proj GEMM.

typedef unsigned short u16;
typedef unsigned int u32;
typedef __attribute__((ext_vector_type(8))) short short8;        // bf16x8 MFMA frag
typedef __attribute__((ext_vector_type(4))) float f32x4;         // MFMA acc frag
typedef __attribute__((ext_vector_type(4))) unsigned short u16x4;
typedef __attribute__((ext_vector_type(8))) unsigned short u16x8;
typedef __attribute__((ext_vector_type(2))) unsigned int u32x2;

#define MFMA16(a, b, c) __builtin_amdgcn_mfma_f32_16x16x32_bf16((a), (b), (c), 0, 0, 0)

__device__ __forceinline__ u16 f2bf(float f) {
  union { __hip_bfloat16 h; u16 u; } cv;
  cv.h = __float2bfloat16(f);
  return cv.u;
}

// async global->LDS, 16B per lane; lds base must be wave-uniform.
__device__ __forceinline__ void gl_lds16(const u16* g, u16* l) {
  __builtin_amdgcn_global_load_lds(
      (const __attribute__((address_space(1))) void*)g,
      (__attribute__((address_space(3))) void*)l, 16, 0, 0);
}

// ---------------------------------------------------------------------------
// X cast: fp32 [n] -> bf16 [n], vectorized 8/thread, grid-stride.
// ---------------------------------------------------------------------------
__global__ __launch_bounds__(256) void xcast_kernel(const float* __restrict__ in,
                                                    u16* __restrict__ out, long n8) {
  long stride = (long)gridDim.x * 256;
  for (long i = blockIdx.x * 256L + threadIdx.x; i < n8; i += stride) {
    f32x4 a = *(const f32x4*)(in + i * 8);
    f32x4 b = *(const f32x4*)(in + i * 8 + 4);
    u16x8 o = {f2bf(a[0]), f2bf(a[1]), f2bf(a[2]), f2bf(a[3]),
               f2bf(b[0]), f2bf(b[1]), f2bf(b[2]), f2bf(b[3])};
    *(u16x8*)(out + i * 8) = o;
  }
}

// ---------------------------------------------------------------------------
// Weight transpose + fp32->bf16 cast: in [m][R][C] fp32 -> out [m][C][R] bf16
// ---------------------------------------------------------------------------
__global__ __launch_bounds__(256) void wtrans_kernel(const float* __restrict__ in,
                                                     u16* __restrict__ out, int R, int C) {
  __shared__ float t[32][33];
  int m = blockIdx.z;
  const float* pin = in + (size_t)m * R * C;
  u16* pout = out + (size_t)m * R * C;
  int c0 = blockIdx.x * 32, r0 = blockIdx.y * 32;
  int tx = threadIdx.x, ty = threadIdx.y;  // (32, 8)
#pragma unroll
  for (int i = 0; i < 4; ++i) {
    int r = ty + i * 8;
    t[r][tx] = pin[(size_t)(r0 + r) * C + c0 + tx];
  }
  __syncthreads();
#pragma unroll
  for (int i = 0; i < 4; ++i) {
    int r = ty + i * 8;
    pout[(size_t)(c0 + r) * R + r0 + tx] = f2bf(t[tx][r]);
  }
}

// ---------------------------------------------------------------------------
// QKV GEMM: xb[m][2048][512] bf16 x wT[m][1536][512] bf16 -> scatter q/k/vT.
// 256x128 tile, BK=32, 8 waves (4Mx2N, 64x64 each). 3 LDS buffers, depth-2
// counted vmcnt(3), one s_barrier per K-step, slot-XOR read swizzle with
// pre-swizzled global source. Grid 768 1-D XCD-affine.
// ---------------------------------------------------------------------------
__global__ __launch_bounds__(512) void qkv_gemm_kernel(const u16* __restrict__ XB,
                                                       const u16* __restrict__ WT,
                                                       u16* __restrict__ Q,
                                                       u16* __restrict__ K,
                                                       u16* __restrict__ VT) {
  __shared__ __attribute__((aligned(16))) u16 As[3][256 * 32];  // 3 x 16 KB
  __shared__ __attribute__((aligned(16))) u16 Bs[3][128 * 32];  // 3 x 8 KB
  int bid = blockIdx.x;                     // 768 blocks
  int wgid = (bid & 7) * 96 + (bid >> 3);   // XCD-affine (768 % 8 == 0)
  int m = wgid / 96;
  int rem = wgid % 96;
  int r0 = (rem / 12) * 256, c0 = (rem % 12) * 128;
  const u16* A = XB + (size_t)m * 2048 * 512;
  const u16* BT = WT + (size_t)m * 1536 * 512;
  int t = threadIdx.x;
  int lane = t & 63, w = t >> 6;            // 8 waves
  int wr = (w >> 1) * 64, wc = (w & 1) * 64;
  int fr = lane & 15, fc = lane >> 4;

  // A: 1024 16B-units (256 rows x 4 slots); thread covers u=t and u=512+t.
  // B: 512 units (128 rows), u=t. gchunk = slot ^ ((row>>1)&3).
  int rA0 = t >> 2, sA0 = (t & 3) ^ ((rA0 >> 1) & 3);
  int rA1 = 128 + (t >> 2), sA1 = (t & 3) ^ ((rA1 >> 1) & 3);

  f32x4 acc[4][4];
#pragma unroll
  for (int i = 0; i < 4; ++i)
#pragma unroll
    for (int j = 0; j < 4; ++j) acc[i][j] = f32x4{0.f, 0.f, 0.f, 0.f};

#define QKV_STAGE(tile)                                                            \
  {                                                                                \
    int kk_ = (tile) * 32;                                                         \
    int b_ = (tile) % 3;                                                           \
    gl_lds16(A + (size_t)(r0 + rA0) * 512 + kk_ + sA0 * 8, &As[b_][w * 512]);      \
    gl_lds16(A + (size_t)(r0 + rA1) * 512 + kk_ + sA1 * 8, &As[b_][4096 + w * 512]); \
    gl_lds16(BT + (size_t)(c0 + rA0) * 512 + kk_ + sA0 * 8, &Bs[b_][w * 512]);     \
  }

#define QKV_COMPUTE(tile)                                                          \
  {                                                                                \
    int b_ = (tile) % 3;                                                           \
    short8 af[4], bf_[4];                                                          \
    _Pragma("unroll") for (int i = 0; i < 4; ++i) {                                \
      int row = wr + i * 16 + fr;                                                  \
      int sl = fc ^ ((row >> 1) & 3);                                              \
      af[i] = *(const short8*)&As[b_][row * 32 + sl * 8];                          \
    }                                                                              \
    _Pragma("unroll") for (int j = 0; j < 4; ++j) {                                \
      int row = wc + j * 16 + fr;                                                  \
      int sl = fc ^ ((row >> 1) & 3);                                              \
      bf_[j] = *(const short8*)&Bs[b_][row * 32 + sl * 8];                         \
    }                                                                              \
    _Pragma("unroll") for (int i = 0; i < 4; ++i)                                  \
      _Pragma("unroll") for (int j = 0; j < 4; ++j)                                \
        acc[i][j] = MFMA16(af[i], bf_[j], acc[i][j]);                              \
  }

  QKV_STAGE(0);
  QKV_STAGE(1);
  for (int ks = 0; ks < 14; ++ks) {
    asm volatile("s_waitcnt vmcnt(3)" ::: "memory");  // tile ks done; ks+1 in flight
    __builtin_amdgcn_sched_barrier(0);
    __builtin_amdgcn_s_barrier();
    QKV_STAGE(ks + 2);
    QKV_COMPUTE(ks);
    __builtin_amdgcn_sched_barrier(0);
  }
  asm volatile("s_waitcnt vmcnt(0)" ::: "memory");
  __builtin_amdgcn_sched_barrier(0);
  __builtin_amdgcn_s_barrier();
  QKV_COMPUTE(14);
  QKV_COMPUTE(15);

  int seg = c0 >> 9;  // uniform per block: 0=q, 1=k, 2=v
  if (seg == 2) {
#pragma unroll
    for (int i = 0; i < 4; ++i)
#pragma unroll
      for (int j = 0; j < 4; ++j) {
        int s0 = r0 + wr + i * 16 + fc * 4;
        int gcol = c0 + wc + j * 16 + fr;
        int cc = gcol & 511;
        int hh = cc >> 6, hd = cc & 63;
        int b = s0 >> 9, s = s0 & 511;
        size_t headoff = (size_t)((m * 4 + b) * 8 + hh) * 32768;
        u16x4 pk = {f2bf(acc[i][j][0]), f2bf(acc[i][j][1]),
                    f2bf(acc[i][j][2]), f2bf(acc[i][j][3])};
        *(u16x4*)(VT + headoff + (size_t)hd * 512 + s) = pk;
      }
  } else {
#pragma unroll
    for (int i = 0; i < 4; ++i)
#pragma unroll
      for (int j = 0; j < 4; ++j)
#pragma unroll
        for (int r = 0; r < 4; ++r) {
          int grow = r0 + wr + i * 16 + fc * 4 + r;
          int gcol = c0 + wc + j * 16 + fr;
          int b = grow >> 9, s = grow & 511;
          int cc = gcol & 511;
          int hh = cc >> 6, hd = cc & 63;
          size_t headoff = (size_t)((m * 4 + b) * 8 + hh) * 32768;
          u16 val = f2bf(acc[i][j][r]);
          if (seg == 0) Q[headoff + s * 64 + hd] = val;
          else          K[headoff + s * 64 + hd] = val;
        }
  }
}

// ---------------------------------------------------------------------------
// Flash attention, paired q-tiles. Grid 1024: bid>>8 = p (0..3), bid&255 = head.
// Block handles q-tiles qtA=p and qtB=7-p: uniform 9 tile-computes/block, and
// K/V tiles kt<=qtA are staged ONCE for both. K/V staged via global_load_lds
// (linear [64][64], slot^=(row&7) read swizzle), double-buffered, counted
// vmcnt(4), raw s_barriers (no vmcnt-0 drain in loop).
// ---------------------------------------------------------------------------
__global__ __launch_bounds__(256) void attn_kernel(const u16* __restrict__ Qg,
                                                   const u16* __restrict__ Kg,
                                                   const u16* __restrict__ VTg,
                                                   u16* __restrict__ Yg) {
  __shared__ __attribute__((aligned(16))) u16 Ks[2][64 * 64];  // 2 x 8 KB
  __shared__ __attribute__((aligned(16))) u16 Vs[2][64 * 64];  // 2 x 8 KB
  __shared__ u16 Pl[4][16][72];
  int bid = blockIdx.x;
  int p = bid >> 8;
  int g = bid & 255;
  int h = g & 7, mb = g >> 3;
  int qtA = p, qtB = 7 - p;
  int t = threadIdx.x, lane = t & 63, w = t >> 6;
  int fr = lane & 15, fc = lane >> 4;
  size_t hoff = ((size_t)mb * 8 + h) * 32768;
  const u16* Q = Qg + hoff;
  const u16* K = Kg + hoff;
  const u16* V = VTg + hoff;  // [hd][s]
  const float SC = 0.125f * 1.44269504088896340736f;  // 1/sqrt(HD) * log2(e)

  int qrowA = qtA * 64 + w * 16 + fr;
  int qrowB = qtB * 64 + w * 16 + fr;
  short8 qA0 = *(const short8*)(Q + (size_t)qrowA * 64 + fc * 8);
  short8 qA1 = *(const short8*)(Q + (size_t)qrowA * 64 + 32 + fc * 8);
  short8 qB0 = *(const short8*)(Q + (size_t)qrowB * 64 + fc * 8);
  short8 qB1 = *(const short8*)(Q + (size_t)qrowB * 64 + 32 + fc * 8);

  f32x4 accA[4], accB[4];
#pragma unroll
  for (int d = 0; d < 4; ++d) {
    accA[d] = f32x4{0.f, 0.f, 0.f, 0.f};
    accB[d] = f32x4{0.f, 0.f, 0.f, 0.f};
  }
  float mstA = -1e30f, lstA = 0.f, mstB = -1e30f, lstB = 0.f;

  // staging: K/V tile = 64 rows x 64 hw = 512 16B-units (8 slots/row);
  // thread covers u=t and u=256+t. gchunk = slot ^ (row&7).
  int sr0 = t >> 3, ss0 = (t & 7) ^ (sr0 & 7);
  int sr1 = 32 + (t >> 3), ss1 = (t & 7) ^ (sr1 & 7);

#define ATTN_STAGE(kt_, buf_)                                                     \
  {                                                                               \
    int kb_ = (kt_) * 64;                                                         \
    gl_lds16(K + (size_t)(kb_ + sr0) * 64 + ss0 * 8, &Ks[buf_][w * 512]);         \
    gl_lds16(K + (size_t)(kb_ + sr1) * 64 + ss1 * 8, &Ks[buf_][2048 + w * 512]);  \
    gl_lds16(V + (size_t)sr0 * 512 + kb_ + ss0 * 8, &Vs[buf_][w * 512]);          \
    gl_lds16(V + (size_t)sr1 * 512 + kb_ + ss1 * 8, &Vs[buf_][2048 + w * 512]);   \
  }

  int qloc = w * 16 + fr;
  ATTN_STAGE(0, 0);

  for (int kt = 0; kt <= qtB; ++kt) {
    int cur = kt & 1;
    if (kt < qtB) {
      ATTN_STAGE(kt + 1, cur ^ 1);
      asm volatile("s_waitcnt vmcnt(4)" ::: "memory");  // tile kt done
    } else {
      asm volatile("s_waitcnt vmcnt(0)" ::: "memory");
    }
    __builtin_amdgcn_sched_barrier(0);
    __builtin_amdgcn_s_barrier();  // all waves' DMA for buf cur landed

    auto tile_compute = [&](const short8& qf0, const short8& qf1, f32x4(&acc)[4],
                            float& mst, float& lst, bool diag) {
      f32x4 st[4];
#pragma unroll
      for (int sub = 0; sub < 4; ++sub) {
        int row = sub * 16 + fr;
        short8 kf0 = *(const short8*)&Ks[cur][row * 64 + ((fc ^ (row & 7)) & 7) * 8];
        short8 kf1 = *(const short8*)&Ks[cur][row * 64 + (((4 + fc) ^ (row & 7)) & 7) * 8];
        f32x4 z = f32x4{0.f, 0.f, 0.f, 0.f};
        z = MFMA16(kf0, qf0, z);
        st[sub] = MFMA16(kf1, qf1, z);
      }
      float pv[4][4];
      float mt = -3e30f;
#pragma unroll
      for (int sub = 0; sub < 4; ++sub)
#pragma unroll
        for (int r = 0; r < 4; ++r) {
          float v = st[sub][r] * SC;
          if (diag && (sub * 16 + fc * 4 + r) > qloc) v = -1e30f;
          pv[sub][r] = v;
          mt = fmaxf(mt, v);
        }
      mt = fmaxf(mt, __shfl_xor(mt, 16));
      mt = fmaxf(mt, __shfl_xor(mt, 32));
      float mn = fmaxf(mst, mt);
      float al = __builtin_amdgcn_exp2f(mst - mn);
      mst = mn;
      float rs = 0.f;
#pragma unroll
      for (int sub = 0; sub < 4; ++sub)
#pragma unroll
        for (int r = 0; r < 4; ++r) {
          float e = __builtin_amdgcn_exp2f(pv[sub][r] - mn);
          pv[sub][r] = e;
          rs += e;
        }
      rs += __shfl_xor(rs, 16);
      rs += __shfl_xor(rs, 32);
      lst = lst * al + rs;
#pragma unroll
      for (int d = 0; d < 4; ++d) acc[d] *= al;

#pragma unroll
      for (int sub = 0; sub < 4; ++sub) {
        u32 lo = (u32)f2bf(pv[sub][0]) | ((u32)f2bf(pv[sub][1]) << 16);
        u32 hi = (u32)f2bf(pv[sub][2]) | ((u32)f2bf(pv[sub][3]) << 16);
        *(u32x2*)&Pl[w][fr][sub * 16 + fc * 4] = u32x2{lo, hi};
      }
#pragma unroll
      for (int dt = 0; dt < 4; ++dt)
#pragma unroll
        for (int kc = 0; kc < 2; ++kc) {
          int row = dt * 16 + fr;
          short8 vf = *(const short8*)&Vs[cur][row * 64 + (((kc * 4 + fc) ^ (row & 7)) & 7) * 8];
          short8 pb = *(const short8*)&Pl[w][fr][kc * 32 + fc * 8];
          acc[dt] = MFMA16(vf, pb, acc[dt]);
        }
    };

    if (kt <= qtA) tile_compute(qA0, qA1, accA, mstA, lstA, kt == qtA);
    tile_compute(qB0, qB1, accB, mstB, lstB, kt == qtB);

    asm volatile("s_waitcnt lgkmcnt(0)" ::: "memory");
    __builtin_amdgcn_sched_barrier(0);
    __builtin_amdgcn_s_barrier();  // all reads of buf cur done before next DMA
  }

  float invA = 1.0f / lstA, invB = 1.0f / lstB;
#pragma unroll
  for (int dt = 0; dt < 4; ++dt) {
    u16x4 oA = {f2bf(accA[dt][0] * invA), f2bf(accA[dt][1] * invA),
                f2bf(accA[dt][2] * invA), f2bf(accA[dt][3] * invA)};
    *(u16x4*)(Yg + ((size_t)mb * 512 + qrowA) * 512 + h * 64 + dt * 16 + fc * 4) = oA;
    u16x4 oB = {f2bf(accB[dt][0] * invB), f2bf(accB[dt][1] * invB),
                f2bf(accB[dt][2] * invB), f2bf(accB[dt][3] * invB)};
    *(u16x4*)(Yg + ((size_t)mb * 512 + qrowB) * 512 + h * 64 + dt * 16 + fc * 4) = oB;
  }
}

// ---------------------------------------------------------------------------
// Projection GEMM: y[m][2048][512] bf16 x projT[m][512][512] -> out fp32.
// Same 256x128 3-buffer counted-vmcnt structure. Grid 256 = one round.
// ---------------------------------------------------------------------------
__global__ __launch_bounds__(512) void proj_gemm_kernel(const u16* __restrict__ Y,
                                                        const u16* __restrict__ PT,
                                                        float* __restrict__ OUT) {
  __shared__ __attribute__((aligned(16))) u16 As[3][256 * 32];
  __shared__ __attribute__((aligned(16))) u16 Bs[3][128 * 32];
  int bid = blockIdx.x;                    // 256 blocks
  int wgid = (bid & 7) * 32 + (bid >> 3);  // XCD-affine
  int m = wgid / 32;
  int rem = wgid % 32;
  int r0 = (rem / 4) * 256, c0 = (rem % 4) * 128;
  const u16* A = Y + (size_t)m * 2048 * 512;
  const u16* BT = PT + (size_t)m * 512 * 512;
  float* C = OUT + (size_t)m * 2048 * 512;
  int t = threadIdx.x;
  int lane = t & 63, w = t >> 6;
  int wr = (w >> 1) * 64, wc = (w & 1) * 64;
  int fr = lane & 15, fc = lane >> 4;

  int rA0 = t >> 2, sA0 = (t & 3) ^ ((rA0 >> 1) & 3);
  int rA1 = 128 + (t >> 2), sA1 = (t & 3) ^ ((rA1 >> 1) & 3);

  f32x4 acc[4][4];
#pragma unroll
  for (int i = 0; i < 4; ++i)
#pragma unroll
    for (int j = 0; j < 4; ++j) acc[i][j] = f32x4{0.f, 0.f, 0.f, 0.f};

#define PROJ_STAGE(tile)                                                           \
  {                                                                                \
    int kk_ = (tile) * 32;                                                         \
    int b_ = (tile) % 3;                                                           \
    gl_lds16(A + (size_t)(r0 + rA0) * 512 + kk_ + sA0 * 8, &As[b_][w * 512]);      \
    gl_lds16(A + (size_t)(r0 + rA1) * 512 + kk_ + sA1 * 8, &As[b_][4096 + w * 512]); \
    gl_lds16(BT + (size_t)(c0 + rA0) * 512 + kk_ + sA0 * 8, &Bs[b_][w * 512]);     \
  }

#define PROJ_COMPUTE(tile)                                                         \
  {                                                                                \
    int b_ = (tile) % 3;                                                           \
    short8 af[4], bf_[4];                                                          \
    _Pragma("unroll") for (int i = 0; i < 4; ++i) {                                \
      int row = wr + i * 16 + fr;                                                  \
      int sl = fc ^ ((row >> 1) & 3);                                              \
      af[i] = *(const short8*)&As[b_][row * 32 + sl * 8];                          \
    }                                                                              \
    _Pragma("unroll") for (int j = 0; j < 4; ++j) {                                \
      int row = wc + j * 16 + fr;                                                  \
      int sl = fc ^ ((row >> 1) & 3);                                              \
      bf_[j] = *(const short8*)&Bs[b_][row * 32 + sl * 8];                         \
    }                                                                              \
    _Pragma("unroll") for (int i = 0; i < 4; ++i)                                  \
      _Pragma("unroll") for (int j = 0; j < 4; ++j)                                \
        acc[i][j] = MFMA16(af[i], bf_[j], acc[i][j]);                              \
  }

  PROJ_STAGE(0);
  PROJ_STAGE(1);
  for (int ks = 0; ks < 14; ++ks) {
    asm volatile("s_waitcnt vmcnt(3)" ::: "memory");
    __builtin_amdgcn_sched_barrier(0);
    __builtin_amdgcn_s_barrier();
    PROJ_STAGE(ks + 2);
    PROJ_COMPUTE(ks);
    __builtin_amdgcn_sched_barrier(0);
  }
  asm volatile("s_waitcnt vmcnt(0)" ::: "memory");
  __builtin_amdgcn_sched_barrier(0);
  __builtin_amdgcn_s_barrier();
  PROJ_COMPUTE(14);
  PROJ_COMPUTE(15);

#pragma unroll
  for (int i = 0; i < 4; ++i)
#pragma unroll
    for (int j = 0; j < 4; ++j)
#pragma unroll
      for (int r = 0; r < 4; ++r) {
        int grow = r0 + wr + i * 16 + fc * 4 + r;
        int gcol = c0 + wc + j * 16 + fr;
        C[(size_t)grow * 512 + gcol] = acc[i][j][r];
      }
}

// ---------------------------------------------------------------------------
extern "C" void kernel_launch(void* const* d_in, const int* in_sizes, int n_in,
                              void* d_out, int out_size, void* d_ws, size_t ws_size,
                              hipStream_t stream) {
  const float* x = (const float*)d_in[0];      // [8][4][512][512]
  const float* wqkv = (const float*)d_in[1];   // [8][512][1536]
  const float* wproj = (const float*)d_in[2];  // [8][512][512]
  float* out = (float*)d_out;                  // [8][4][512][512]

  u16* p = (u16*)d_ws;
  u16* wqkvT = p;  p += (size_t)8 * 1536 * 512;  // bf16 [m][1536][512]
  u16* wprojT = p; p += (size_t)8 * 512 * 512;   // bf16 [m][512][512]
  u16* qb = p;     p += (size_t)8388608;         // bf16 [mb*8+h][512][64]
  u16* kb = p;     p += (size_t)8388608;         // bf16 [mb*8+h][512][64]
  u16* vtb = p;    p += (size_t)8388608;         // bf16 [mb*8+h][64][512]
  u16* xyb = p;    p += (size_t)8388608;         // bf16: xb for qkv, then yb

  xcast_kernel<<<2048, 256, 0, stream>>>(x, xyb, (long)8 * 4 * 512 * 512 / 8);
  wtrans_kernel<<<dim3(48, 16, 8), dim3(32, 8), 0, stream>>>(wqkv, wqkvT, 512, 1536);
  wtrans_kernel<<<dim3(16, 16, 8), dim3(32, 8), 0, stream>>>(wproj, wprojT, 512, 512);
  qkv_gemm_kernel<<<768, 512, 0, stream>>>(xyb, wqkvT, qb, kb, vtb);
  attn_kernel<<<1024, 256, 0, stream>>>(qb, kb, vtb, xyb);
  proj_gemm_kernel<<<256, 512, 0, stream>>>(xyb, wprojT, out);
}

// Round 8
// 187.992 us; speedup vs baseline: 1.6646x; 1.0127x over previous
//
#include <hip/hip_runtime.h>
#include <hip/hip_bf16.h>

// Problem: M=8, B=4, S=512, D=512, H=8, HD=64.
// Pipeline: prep (xcast + wqkv^T + wproj^T fused) -> QKV GEMM (256x128, 3-buf
// counted-vmcnt, swizzle) -> paired-tile flash attention (3-buf counted-vmcnt)
// -> proj GEMM.

typedef unsigned short u16;
typedef unsigned int u32;
typedef __attribute__((ext_vector_type(8))) short short8;        // bf16x8 MFMA frag
typedef __attribute__((ext_vector_type(4))) float f32x4;         // MFMA acc frag
typedef __attribute__((ext_vector_type(4))) unsigned short u16x4;
typedef __attribute__((ext_vector_type(8))) unsigned short u16x8;
typedef __attribute__((ext_vector_type(2))) unsigned int u32x2;

#define MFMA16(a, b, c) __builtin_amdgcn_mfma_f32_16x16x32_bf16((a), (b), (c), 0, 0, 0)

__device__ __forceinline__ u16 f2bf(float f) {
  union { __hip_bfloat16 h; u16 u; } cv;
  cv.h = __float2bfloat16(f);
  return cv.u;
}

// async global->LDS, 16B per lane; lds base must be wave-uniform.
__device__ __forceinline__ void gl_lds16(const u16* g, u16* l) {
  __builtin_amdgcn_global_load_lds(
      (const __attribute__((address_space(1))) void*)g,
      (__attribute__((address_space(3))) void*)l, 16, 0, 0);
}

// ---------------------------------------------------------------------------
// Fused prep: blocks [0,1024) xcast; [1024,7168) wqkv^T; [7168,9216) wproj^T.
// ---------------------------------------------------------------------------
__global__ __launch_bounds__(256) void prep_kernel(const float* __restrict__ x,
                                                   u16* __restrict__ xb,
                                                   const float* __restrict__ wqkv,
                                                   u16* __restrict__ wqkvT,
                                                   const float* __restrict__ wproj,
                                                   u16* __restrict__ wprojT) {
  __shared__ float tsh[32][33];
  int bid = blockIdx.x;
  int t = threadIdx.x;
  if (bid < 1024) {
    // xcast: 8.4M fp32 -> bf16, 8/thread/iter, 4 iters
    const long n8 = (long)8 * 4 * 512 * 512 / 8;  // 1048576
    for (long i = (long)bid * 256 + t; i < n8; i += 1024L * 256) {
      f32x4 a = *(const f32x4*)(x + i * 8);
      f32x4 b = *(const f32x4*)(x + i * 8 + 4);
      u16x8 o = {f2bf(a[0]), f2bf(a[1]), f2bf(a[2]), f2bf(a[3]),
                 f2bf(b[0]), f2bf(b[1]), f2bf(b[2]), f2bf(b[3])};
      *(u16x8*)(xb + i * 8) = o;
    }
    return;
  }
  const float* pin;
  u16* pout;
  int R = 512, C, r0, c0;
  if (bid < 7168) {
    int id = bid - 1024;             // 6144 = 8 x 16 x 48
    int m = id / 768, rem = id % 768;
    int ry = rem / 48, cx = rem % 48;
    C = 1536; r0 = ry * 32; c0 = cx * 32;
    pin = wqkv + (size_t)m * 512 * 1536;
    pout = wqkvT + (size_t)m * 512 * 1536;
  } else {
    int id = bid - 7168;             // 2048 = 8 x 16 x 16
    int m = id / 256, rem = id % 256;
    int ry = rem / 16, cx = rem % 16;
    C = 512; r0 = ry * 32; c0 = cx * 32;
    pin = wproj + (size_t)m * 512 * 512;
    pout = wprojT + (size_t)m * 512 * 512;
  }
  int tx = t & 31, ty = t >> 5;  // (32, 8)
#pragma unroll
  for (int i = 0; i < 4; ++i) {
    int r = ty + i * 8;
    tsh[r][tx] = pin[(size_t)(r0 + r) * C + c0 + tx];
  }
  __syncthreads();
#pragma unroll
  for (int i = 0; i < 4; ++i) {
    int r = ty + i * 8;
    pout[(size_t)(c0 + r) * R + r0 + tx] = f2bf(tsh[tx][r]);
  }
}

// ---------------------------------------------------------------------------
// QKV GEMM: xb[m][2048][512] bf16 x wT[m][1536][512] bf16 -> scatter q/k/vT.
// 256x128 tile, BK=32, 8 waves (4Mx2N, 64x64 each). 3 LDS buffers, depth-2
// counted vmcnt(3), one s_barrier per K-step, slot-XOR read swizzle with
// pre-swizzled global source. Grid 768 1-D XCD-affine.
// ---------------------------------------------------------------------------
__global__ __launch_bounds__(512) void qkv_gemm_kernel(const u16* __restrict__ XB,
                                                       const u16* __restrict__ WT,
                                                       u16* __restrict__ Q,
                                                       u16* __restrict__ K,
                                                       u16* __restrict__ VT) {
  __shared__ __attribute__((aligned(16))) u16 As[3][256 * 32];  // 3 x 16 KB
  __shared__ __attribute__((aligned(16))) u16 Bs[3][128 * 32];  // 3 x 8 KB
  int bid = blockIdx.x;                     // 768 blocks
  int wgid = (bid & 7) * 96 + (bid >> 3);   // XCD-affine (768 % 8 == 0)
  int m = wgid / 96;
  int rem = wgid % 96;
  int r0 = (rem / 12) * 256, c0 = (rem % 12) * 128;
  const u16* A = XB + (size_t)m * 2048 * 512;
  const u16* BT = WT + (size_t)m * 1536 * 512;
  int t = threadIdx.x;
  int lane = t & 63, w = t >> 6;            // 8 waves
  int wr = (w >> 1) * 64, wc = (w & 1) * 64;
  int fr = lane & 15, fc = lane >> 4;

  int rA0 = t >> 2, sA0 = (t & 3) ^ ((rA0 >> 1) & 3);
  int rA1 = 128 + (t >> 2), sA1 = (t & 3) ^ ((rA1 >> 1) & 3);

  f32x4 acc[4][4];
#pragma unroll
  for (int i = 0; i < 4; ++i)
#pragma unroll
    for (int j = 0; j < 4; ++j) acc[i][j] = f32x4{0.f, 0.f, 0.f, 0.f};

#define QKV_STAGE(tile)                                                            \
  {                                                                                \
    int kk_ = (tile) * 32;                                                         \
    int b_ = (tile) % 3;                                                           \
    gl_lds16(A + (size_t)(r0 + rA0) * 512 + kk_ + sA0 * 8, &As[b_][w * 512]);      \
    gl_lds16(A + (size_t)(r0 + rA1) * 512 + kk_ + sA1 * 8, &As[b_][4096 + w * 512]); \
    gl_lds16(BT + (size_t)(c0 + rA0) * 512 + kk_ + sA0 * 8, &Bs[b_][w * 512]);     \
  }

#define QKV_COMPUTE(tile)                                                          \
  {                                                                                \
    int b_ = (tile) % 3;                                                           \
    short8 af[4], bf_[4];                                                          \
    _Pragma("unroll") for (int i = 0; i < 4; ++i) {                                \
      int row = wr + i * 16 + fr;                                                  \
      int sl = fc ^ ((row >> 1) & 3);                                              \
      af[i] = *(const short8*)&As[b_][row * 32 + sl * 8];                          \
    }                                                                              \
    _Pragma("unroll") for (int j = 0; j < 4; ++j) {                                \
      int row = wc + j * 16 + fr;                                                  \
      int sl = fc ^ ((row >> 1) & 3);                                              \
      bf_[j] = *(const short8*)&Bs[b_][row * 32 + sl * 8];                         \
    }                                                                              \
    _Pragma("unroll") for (int i = 0; i < 4; ++i)                                  \
      _Pragma("unroll") for (int j = 0; j < 4; ++j)                                \
        acc[i][j] = MFMA16(af[i], bf_[j], acc[i][j]);                              \
  }

  QKV_STAGE(0);
  QKV_STAGE(1);
  for (int ks = 0; ks < 14; ++ks) {
    asm volatile("s_waitcnt vmcnt(3)" ::: "memory");  // tile ks done; ks+1 in flight
    __builtin_amdgcn_sched_barrier(0);
    __builtin_amdgcn_s_barrier();
    QKV_STAGE(ks + 2);
    QKV_COMPUTE(ks);
    __builtin_amdgcn_sched_barrier(0);
  }
  asm volatile("s_waitcnt vmcnt(0)" ::: "memory");
  __builtin_amdgcn_sched_barrier(0);
  __builtin_amdgcn_s_barrier();
  QKV_COMPUTE(14);
  QKV_COMPUTE(15);

  int seg = c0 >> 9;  // uniform per block: 0=q, 1=k, 2=v
  if (seg == 2) {
#pragma unroll
    for (int i = 0; i < 4; ++i)
#pragma unroll
      for (int j = 0; j < 4; ++j) {
        int s0 = r0 + wr + i * 16 + fc * 4;
        int gcol = c0 + wc + j * 16 + fr;
        int cc = gcol & 511;
        int hh = cc >> 6, hd = cc & 63;
        int b = s0 >> 9, s = s0 & 511;
        size_t headoff = (size_t)((m * 4 + b) * 8 + hh) * 32768;
        u16x4 pk = {f2bf(acc[i][j][0]), f2bf(acc[i][j][1]),
                    f2bf(acc[i][j][2]), f2bf(acc[i][j][3])};
        *(u16x4*)(VT + headoff + (size_t)hd * 512 + s) = pk;
      }
  } else {
#pragma unroll
    for (int i = 0; i < 4; ++i)
#pragma unroll
      for (int j = 0; j < 4; ++j)
#pragma unroll
        for (int r = 0; r < 4; ++r) {
          int grow = r0 + wr + i * 16 + fc * 4 + r;
          int gcol = c0 + wc + j * 16 + fr;
          int b = grow >> 9, s = grow & 511;
          int cc = gcol & 511;
          int hh = cc >> 6, hd = cc & 63;
          size_t headoff = (size_t)((m * 4 + b) * 8 + hh) * 32768;
          u16 val = f2bf(acc[i][j][r]);
          if (seg == 0) Q[headoff + s * 64 + hd] = val;
          else          K[headoff + s * 64 + hd] = val;
        }
  }
}

// ---------------------------------------------------------------------------
// Flash attention, paired q-tiles, 3-buffer depth-2 counted-vmcnt pipeline.
// Grid 1024: bid>>8 = p (0..3), bid&255 = head. Block handles qtA=p, qtB=7-p
// (uniform 9 tile-computes). K/V staged via global_load_lds (linear [64][64],
// slot^=(row&7) read swizzle). ONE s_barrier per k-tile: DMA at kt targets
// buf (kt+2)%3 whose reads (iteration kt-1) completed before this barrier.
// ---------------------------------------------------------------------------
__global__ __launch_bounds__(256) void attn_kernel(const u16* __restrict__ Qg,
                                                   const u16* __restrict__ Kg,
                                                   const u16* __restrict__ VTg,
                                                   u16* __restrict__ Yg) {
  __shared__ __attribute__((aligned(16))) u16 Ks[3][64 * 64];  // 3 x 8 KB
  __shared__ __attribute__((aligned(16))) u16 Vs[3][64 * 64];  // 3 x 8 KB
  __shared__ u16 Pl[4][16][72];
  int bid = blockIdx.x;
  int p = bid >> 8;
  int g = bid & 255;
  int h = g & 7, mb = g >> 3;
  int qtA = p, qtB = 7 - p;
  int t = threadIdx.x, lane = t & 63, w = t >> 6;
  int fr = lane & 15, fc = lane >> 4;
  size_t hoff = ((size_t)mb * 8 + h) * 32768;
  const u16* Q = Qg + hoff;
  const u16* K = Kg + hoff;
  const u16* V = VTg + hoff;  // [hd][s]
  const float SC = 0.125f * 1.44269504088896340736f;  // 1/sqrt(HD) * log2(e)

  int qrowA = qtA * 64 + w * 16 + fr;
  int qrowB = qtB * 64 + w * 16 + fr;
  short8 qA0 = *(const short8*)(Q + (size_t)qrowA * 64 + fc * 8);
  short8 qA1 = *(const short8*)(Q + (size_t)qrowA * 64 + 32 + fc * 8);
  short8 qB0 = *(const short8*)(Q + (size_t)qrowB * 64 + fc * 8);
  short8 qB1 = *(const short8*)(Q + (size_t)qrowB * 64 + 32 + fc * 8);

  f32x4 accA[4], accB[4];
#pragma unroll
  for (int d = 0; d < 4; ++d) {
    accA[d] = f32x4{0.f, 0.f, 0.f, 0.f};
    accB[d] = f32x4{0.f, 0.f, 0.f, 0.f};
  }
  float mstA = -1e30f, lstA = 0.f, mstB = -1e30f, lstB = 0.f;

  // staging: tile = 64 rows x 64 hw = 512 16B-units (8 slots/row);
  // thread covers u=t and u=256+t. gchunk = slot ^ (row&7).
  int sr0 = t >> 3, ss0 = (t & 7) ^ (sr0 & 7);
  int sr1 = 32 + (t >> 3), ss1 = (t & 7) ^ (sr1 & 7);

#define ATTN_STAGE(kt_, buf_)                                                     \
  {                                                                               \
    int kb_ = (kt_) * 64;                                                         \
    gl_lds16(K + (size_t)(kb_ + sr0) * 64 + ss0 * 8, &Ks[buf_][w * 512]);         \
    gl_lds16(K + (size_t)(kb_ + sr1) * 64 + ss1 * 8, &Ks[buf_][2048 + w * 512]);  \
    gl_lds16(V + (size_t)sr0 * 512 + kb_ + ss0 * 8, &Vs[buf_][w * 512]);          \
    gl_lds16(V + (size_t)sr1 * 512 + kb_ + ss1 * 8, &Vs[buf_][2048 + w * 512]);   \
  }

  int qloc = w * 16 + fr;
  ATTN_STAGE(0, 0);
  ATTN_STAGE(1, 1);
  int cur = 0;

  for (int kt = 0; kt <= qtB; ++kt) {
    if (kt < qtB) {
      asm volatile("s_waitcnt vmcnt(4)" ::: "memory");  // tile kt landed; kt+1 in flight
    } else {
      asm volatile("s_waitcnt vmcnt(0)" ::: "memory");
    }
    __builtin_amdgcn_sched_barrier(0);
    __builtin_amdgcn_s_barrier();  // all waves' DMA for buf cur landed; buf (kt+2)%3 reads done
    if (kt + 2 <= qtB) {
      int nb = (cur >= 1) ? cur - 1 : 2;  // (kt+2)%3
      ATTN_STAGE(kt + 2, nb);
    }

    auto tile_compute = [&](const short8& qf0, const short8& qf1, f32x4(&acc)[4],
                            float& mst, float& lst, bool diag) {
      f32x4 st[4];
#pragma unroll
      for (int sub = 0; sub < 4; ++sub) {
        int row = sub * 16 + fr;
        short8 kf0 = *(const short8*)&Ks[cur][row * 64 + ((fc ^ (row & 7)) & 7) * 8];
        short8 kf1 = *(const short8*)&Ks[cur][row * 64 + (((4 + fc) ^ (row & 7)) & 7) * 8];
        f32x4 z = f32x4{0.f, 0.f, 0.f, 0.f};
        z = MFMA16(kf0, qf0, z);
        st[sub] = MFMA16(kf1, qf1, z);
      }
      float pv[4][4];
      float mt = -3e30f;
#pragma unroll
      for (int sub = 0; sub < 4; ++sub)
#pragma unroll
        for (int r = 0; r < 4; ++r) {
          float v = st[sub][r] * SC;
          if (diag && (sub * 16 + fc * 4 + r) > qloc) v = -1e30f;
          pv[sub][r] = v;
          mt = fmaxf(mt, v);
        }
      mt = fmaxf(mt, __shfl_xor(mt, 16));
      mt = fmaxf(mt, __shfl_xor(mt, 32));
      float mn = fmaxf(mst, mt);
      float al = __builtin_amdgcn_exp2f(mst - mn);
      mst = mn;
      float rs = 0.f;
#pragma unroll
      for (int sub = 0; sub < 4; ++sub)
#pragma unroll
        for (int r = 0; r < 4; ++r) {
          float e = __builtin_amdgcn_exp2f(pv[sub][r] - mn);
          pv[sub][r] = e;
          rs += e;
        }
      rs += __shfl_xor(rs, 16);
      rs += __shfl_xor(rs, 32);
      lst = lst * al + rs;
#pragma unroll
      for (int d = 0; d < 4; ++d) acc[d] *= al;

#pragma unroll
      for (int sub = 0; sub < 4; ++sub) {
        u32 lo = (u32)f2bf(pv[sub][0]) | ((u32)f2bf(pv[sub][1]) << 16);
        u32 hi = (u32)f2bf(pv[sub][2]) | ((u32)f2bf(pv[sub][3]) << 16);
        *(u32x2*)&Pl[w][fr][sub * 16 + fc * 4] = u32x2{lo, hi};
      }
#pragma unroll
      for (int dt = 0; dt < 4; ++dt)
#pragma unroll
        for (int kc = 0; kc < 2; ++kc) {
          int row = dt * 16 + fr;
          short8 vf = *(const short8*)&Vs[cur][row * 64 + (((kc * 4 + fc) ^ (row & 7)) & 7) * 8];
          short8 pb = *(const short8*)&Pl[w][fr][kc * 32 + fc * 8];
          acc[dt] = MFMA16(vf, pb, acc[dt]);
        }
    };

    if (kt <= qtA) tile_compute(qA0, qA1, accA, mstA, lstA, kt == qtA);
    tile_compute(qB0, qB1, accB, mstB, lstB, kt == qtB);

    __builtin_amdgcn_sched_barrier(0);  // keep this iteration's reads before next barrier
    cur = (cur == 2) ? 0 : cur + 1;
  }

  float invA = 1.0f / lstA, invB = 1.0f / lstB;
#pragma unroll
  for (int dt = 0; dt < 4; ++dt) {
    u16x4 oA = {f2bf(accA[dt][0] * invA), f2bf(accA[dt][1] * invA),
                f2bf(accA[dt][2] * invA), f2bf(accA[dt][3] * invA)};
    *(u16x4*)(Yg + ((size_t)mb * 512 + qrowA) * 512 + h * 64 + dt * 16 + fc * 4) = oA;
    u16x4 oB = {f2bf(accB[dt][0] * invB), f2bf(accB[dt][1] * invB),
                f2bf(accB[dt][2] * invB), f2bf(accB[dt][3] * invB)};
    *(u16x4*)(Yg + ((size_t)mb * 512 + qrowB) * 512 + h * 64 + dt * 16 + fc * 4) = oB;
  }
}

// ---------------------------------------------------------------------------
// Projection GEMM: y[m][2048][512] bf16 x projT[m][512][512] -> out fp32.
// Same 256x128 3-buffer counted-vmcnt structure. Grid 256, XCD-affine.
// ---------------------------------------------------------------------------
__global__ __launch_bounds__(512) void proj_gemm_kernel(const u16* __restrict__ Y,
                                                        const u16* __restrict__ PT,
                                                        float* __restrict__ OUT) {
  __shared__ __attribute__((aligned(16))) u16 As[3][256 * 32];
  __shared__ __attribute__((aligned(16))) u16 Bs[3][128 * 32];
  int bid = blockIdx.x;                    // 256 blocks
  int wgid = (bid & 7) * 32 + (bid >> 3);  // XCD-affine
  int m = wgid / 32;
  int rem = wgid % 32;
  int r0 = (rem / 4) * 256, c0 = (rem % 4) * 128;
  const u16* A = Y + (size_t)m * 2048 * 512;
  const u16* BT = PT + (size_t)m * 512 * 512;
  float* C = OUT + (size_t)m * 2048 * 512;
  int t = threadIdx.x;
  int lane = t & 63, w = t >> 6;
  int wr = (w >> 1) * 64, wc = (w & 1) * 64;
  int fr = lane & 15, fc = lane >> 4;

  int rA0 = t >> 2, sA0 = (t & 3) ^ ((rA0 >> 1) & 3);
  int rA1 = 128 + (t >> 2), sA1 = (t & 3) ^ ((rA1 >> 1) & 3);

  f32x4 acc[4][4];
#pragma unroll
  for (int i = 0; i < 4; ++i)
#pragma unroll
    for (int j = 0; j < 4; ++j) acc[i][j] = f32x4{0.f, 0.f, 0.f, 0.f};

#define PROJ_STAGE(tile)                                                           \
  {                                                                                \
    int kk_ = (tile) * 32;                                                         \
    int b_ = (tile) % 3;                                                           \
    gl_lds16(A + (size_t)(r0 + rA0) * 512 + kk_ + sA0 * 8, &As[b_][w * 512]);      \
    gl_lds16(A + (size_t)(r0 + rA1) * 512 + kk_ + sA1 * 8, &As[b_][4096 + w * 512]); \
    gl_lds16(BT + (size_t)(c0 + rA0) * 512 + kk_ + sA0 * 8, &Bs[b_][w * 512]);     \
  }

#define PROJ_COMPUTE(tile)                                                         \
  {                                                                                \
    int b_ = (tile) % 3;                                                           \
    short8 af[4], bf_[4];                                                          \
    _Pragma("unroll") for (int i = 0; i < 4; ++i) {                                \
      int row = wr + i * 16 + fr;                                                  \
      int sl = fc ^ ((row >> 1) & 3);                                              \
      af[i] = *(const short8*)&As[b_][row * 32 + sl * 8];                          \
    }                                                                              \
    _Pragma("unroll") for (int j = 0; j < 4; ++j) {                                \
      int row = wc + j * 16 + fr;                                                  \
      int sl = fc ^ ((row >> 1) & 3);                                              \
      bf_[j] = *(const short8*)&Bs[b_][row * 32 + sl * 8];                         \
    }                                                                              \
    _Pragma("unroll") for (int i = 0; i < 4; ++i)                                  \
      _Pragma("unroll") for (int j = 0; j < 4; ++j)                                \
        acc[i][j] = MFMA16(af[i], bf_[j], acc[i][j]);                              \
  }

  PROJ_STAGE(0);
  PROJ_STAGE(1);
  for (int ks = 0; ks < 14; ++ks) {
    asm volatile("s_waitcnt vmcnt(3)" ::: "memory");
    __builtin_amdgcn_sched_barrier(0);
    __builtin_amdgcn_s_barrier();
    PROJ_STAGE(ks + 2);
    PROJ_COMPUTE(ks);
    __builtin_amdgcn_sched_barrier(0);
  }
  asm volatile("s_waitcnt vmcnt(0)" ::: "memory");
  __builtin_amdgcn_sched_barrier(0);
  __builtin_amdgcn_s_barrier();
  PROJ_COMPUTE(14);
  PROJ_COMPUTE(15);

#pragma unroll
  for (int i = 0; i < 4; ++i)
#pragma unroll
    for (int j = 0; j < 4; ++j)
#pragma unroll
      for (int r = 0; r < 4; ++r) {
        int grow = r0 + wr + i * 16 + fc * 4 + r;
        int gcol = c0 + wc + j * 16 + fr;
        C[(size_t)grow * 512 + gcol] = acc[i][j][r];
      }
}

// ---------------------------------------------------------------------------
extern "C" void kernel_launch(void* const* d_in, const int* in_sizes, int n_in,
                              void* d_out, int out_size, void* d_ws, size_t ws_size,
                              hipStream_t stream) {
  const float* x = (const float*)d_in[0];      // [8][4][512][512]
  const float* wqkv = (const float*)d_in[1];   // [8][512][1536]
  const float* wproj = (const float*)d_in[2];  // [8][512][512]
  float* out = (float*)d_out;                  // [8][4][512][512]

  u16* p = (u16*)d_ws;
  u16* wqkvT = p;  p += (size_t)8 * 1536 * 512;  // bf16 [m][1536][512]
  u16* wprojT = p; p += (size_t)8 * 512 * 512;   // bf16 [m][512][512]
  u16* qb = p;     p += (size_t)8388608;         // bf16 [mb*8+h][512][64]
  u16* kb = p;     p += (size_t)8388608;         // bf16 [mb*8+h][512][64]
  u16* vtb = p;    p += (size_t)8388608;         // bf16 [mb*8+h][64][512]
  u16* xyb = p;    p += (size_t)8388608;         // bf16: xb for qkv, then yb

  prep_kernel<<<9216, 256, 0, stream>>>(x, xyb, wqkv, wqkvT, wproj, wprojT);
  qkv_gemm_kernel<<<768, 512, 0, stream>>>(xyb, wqkvT, qb, kb, vtb);
  attn_kernel<<<1024, 256, 0, stream>>>(qb, kb, vtb, xyb);
  proj_gemm_kernel<<<256, 512, 0, stream>>>(xyb, wprojT, out);
}